// Round 2
// baseline (1345.082 us; speedup 1.0000x reference)
//
#include <hip/hip_runtime.h>
#include <hip/hip_bf16.h>
#include <math.h>

#define NN 50000
#define NE 800000
#define FE 16
#define CC 64
#define NG 512
#define NCLS 10
#define NCONV 7

struct MlpP { const float* w1; const float* b1; const float* w2; const float* b2; };
struct MlpAll { MlpP p[NCONV]; };

__device__ __forceinline__ int lowerb(const int* __restrict__ a, int n, int key) {
  int lo = 0, hi = n;
  while (lo < hi) { int m = (lo + hi) >> 1; if (a[m] < key) lo = m + 1; else hi = m; }
  return lo;
}

// ---- CSR build ----
__global__ __launch_bounds__(256) void k_hist(const int* __restrict__ ecol, int* __restrict__ cnt) {
  int e = blockIdx.x * 256 + threadIdx.x;
  if (e < NE) atomicAdd(&cnt[ecol[e]], 1);
}

__global__ __launch_bounds__(1024) void k_scan(int* __restrict__ cnt, int* __restrict__ cptr) {
  __shared__ int sc[1024];
  int t = threadIdx.x;
  const int CH = (NN + 1023) / 1024;  // 49
  int s0 = t * CH, s1 = s0 + CH;
  if (s0 > NN) s0 = NN;
  if (s1 > NN) s1 = NN;
  int sum = 0;
  for (int i = s0; i < s1; ++i) sum += cnt[i];
  sc[t] = sum;
  __syncthreads();
  for (int off = 1; off < 1024; off <<= 1) {
    int v = (t >= off) ? sc[t - off] : 0;
    __syncthreads();
    sc[t] += v;
    __syncthreads();
  }
  int run = sc[t] - sum;  // exclusive prefix
  for (int i = s0; i < s1; ++i) {
    int cv = cnt[i];
    cptr[i] = run;
    cnt[i] = run;  // becomes cursor
    run += cv;
  }
  if (t == 1023) cptr[NN] = sc[1023];
}

// ---- CSR scatter: only {src, edge_id} (8B) per slot; 6.4MB footprint stays near-L2 ----
__global__ __launch_bounds__(256) void k_scatter(
    const int* __restrict__ erow, const int* __restrict__ ecol,
    int* __restrict__ cursor, int2* __restrict__ se) {
  int e = blockIdx.x * 256 + threadIdx.x;
  if (e >= NE) return;
  int c = ecol[e];
  int p = atomicAdd(&cursor[c], 1);
  se[p] = make_int2(erow[e], e);
}

// ---- all-7 edge MLPs in EDGE ORDER: coalesced reads + sequential wcsr writes ----
__global__ __launch_bounds__(256) void k_mlp(
    const int* __restrict__ ecol, const float* __restrict__ ea,
    float* __restrict__ wcsr, float* __restrict__ deg, MlpAll mw) {
  int e = blockIdx.x * 256 + threadIdx.x;
  if (e >= NE) return;
  int c = ecol[e];
  float a[16];
  const float4* ea4 = reinterpret_cast<const float4*>(ea + (size_t)e * 16);
  float4 q0 = ea4[0], q1 = ea4[1], q2 = ea4[2], q3 = ea4[3];
  a[0]=q0.x; a[1]=q0.y; a[2]=q0.z; a[3]=q0.w;
  a[4]=q1.x; a[5]=q1.y; a[6]=q1.z; a[7]=q1.w;
  a[8]=q2.x; a[9]=q2.y; a[10]=q2.z; a[11]=q2.w;
  a[12]=q3.x; a[13]=q3.y; a[14]=q3.z; a[15]=q3.w;
  #pragma unroll
  for (int j = 0; j < NCONV; ++j) {
    const float* w1 = mw.p[j].w1;
    const float* b1 = mw.p[j].b1;
    const float* w2 = mw.p[j].w2;
    float z = mw.p[j].b2[0];
    #pragma unroll
    for (int k = 0; k < 16; ++k) {
      float h = b1[k];
      #pragma unroll
      for (int m = 0; m < 16; ++m) h += a[m] * w1[k * 16 + m];
      h = h > 0.f ? h : 0.f;
      z += h * w2[k];
    }
    float wv = 1.f / (1.f + expf(-z));
    wcsr[(size_t)j * NE + e] = wv;     // sequential, coalesced
    atomicAdd(&deg[j * NN + c], wv);   // L2-resident 1.4MB region
  }
}

__global__ __launch_bounds__(256) void k_dis(float* __restrict__ deg) {
  int i = blockIdx.x * 256 + threadIdx.x;
  if (i < NCONV * NN) deg[i] = rsqrtf(deg[i] + 1.0f);  // +1 = self loop; always > 0
}

// transpose the 7 node-linear weights: lwT[j][ci][co] = lw_j[co][ci]
__global__ __launch_bounds__(256) void k_lwt(const float* __restrict__ c1, const float* __restrict__ h1,
                                             const float* __restrict__ h2, float* __restrict__ lwT) {
  int id = blockIdx.x * 256 + threadIdx.x;
  if (id >= NCONV * CC * CC) return;
  int j = id >> 12;
  int r = id & 4095;
  int co = r >> 6, ci = r & 63;
  const float* src = (j == 0) ? c1 : (j <= 3 ? h1 + (j - 1) * 4096 : h2 + (j - 4) * 4096);
  lwT[j * 4096 + ci * 64 + co] = src[co * 64 + ci];
}

// ---- BatchNorm stats: S and SS per channel ----
__global__ __launch_bounds__(256) void k_bnstat(const float* __restrict__ src, float* __restrict__ accum) {
  __shared__ float sS[256], sQ[256];
  int t = threadIdx.x;
  int c = t & 63, rg = t >> 6;
  int base = blockIdx.x * 196;
  float S = 0.f, Q = 0.f;
  for (int rr = rg; rr < 196; rr += 4) {
    int r = base + rr;
    if (r < NN) { float v = src[r * 64 + c]; S += v; Q += v * v; }
  }
  sS[t] = S; sQ[t] = Q;
  __syncthreads();
  if (t < 128) { sS[t] += sS[t + 128]; sQ[t] += sQ[t + 128]; }
  __syncthreads();
  if (t < 64) {
    atomicAdd(&accum[c], sS[t] + sS[t + 64]);
    atomicAdd(&accum[64 + c], sQ[t] + sQ[t + 64]);
  }
}

// ---- fused (BN+ReLU)? -> GEMM -> *dis : dst = f(src) @ lwT * dis[n] ----
__global__ __launch_bounds__(256) void k_gemm(const float* __restrict__ src, const float* __restrict__ lwT,
                                              const float* __restrict__ accum, const float* __restrict__ dis,
                                              float* __restrict__ dst, int useBN) {
  __shared__ float xs[64 * 65];
  int t = threadIdx.x;
  int rows0 = blockIdx.x * 64;
  // stage 64 rows, fused BN+ReLU
  for (int i = 0; i < 16; ++i) {
    int g = t + i * 256;
    int r = g >> 6, ci = g & 63;
    int row = rows0 + r;
    float v = 0.f;
    if (row < NN) v = src[row * 64 + ci];
    if (useBN) {
      float S = accum[ci], SS = accum[64 + ci];
      float mu = S * (1.0f / NN);
      float var = SS * (1.0f / NN) - mu * mu;
      var = var < 0.f ? 0.f : var;
      float rs = rsqrtf(var + 1e-5f);
      v = (v - mu) * rs;
      v = v > 0.f ? v : 0.f;
    }
    xs[r * 65 + ci] = v;
  }
  __syncthreads();
  int lane = t & 63;
  int cobase = __builtin_amdgcn_readfirstlane((t >> 6) << 4);  // wave-uniform -> scalar weight loads
  float acc[16];
  #pragma unroll
  for (int u = 0; u < 16; ++u) acc[u] = 0.f;
  #pragma unroll 8
  for (int ci = 0; ci < 64; ++ci) {
    float xv = xs[lane * 65 + ci];
    const float* wrow = lwT + ci * 64 + cobase;
    #pragma unroll
    for (int u = 0; u < 16; ++u) acc[u] += xv * wrow[u];
  }
  __syncthreads();
  int row = rows0 + lane;
  float d = (row < NN) ? dis[row] : 0.f;
  #pragma unroll
  for (int u = 0; u < 16; ++u) xs[lane * 65 + cobase + u] = acc[u] * d;
  __syncthreads();
  for (int i = 0; i < 16; ++i) {
    int g = t + i * 256;
    int r = g >> 6, co = g & 63;
    int orow = rows0 + r;
    if (orow < NN) dst[orow * 64 + co] = xs[r * 65 + co];
  }
}

// ---- aggregation: wave per node, lane = channel; weight gathered via edge id ----
// mode 0: out = v ; mode 1: s=v+skipA -> out=s, outX1=s ; mode 2: out = relu(v+skipA+skipX1)
__global__ __launch_bounds__(256) void k_agg(const float* __restrict__ T, const float* __restrict__ wcsr,
                                             const int2* __restrict__ se, const int* __restrict__ cptr,
                                             const float* __restrict__ dis, float* __restrict__ out,
                                             const float* __restrict__ skipA, const float* __restrict__ skipX1,
                                             float* __restrict__ outX1, int mode) {
  int t = threadIdx.x;
  int n = blockIdx.x * 4 + (t >> 6);
  if (n >= NN) return;
  int lane = t & 63;
  int lo = cptr[n], hi = cptr[n + 1];
  float acc = T[n * 64 + lane];  // self loop (xls already has dis[n] folded in)
  for (int k = lo; k < hi; ++k) {
    int2 p = se[k];
    float w = wcsr[p.y];         // broadcast 4B gather from L2-resident 3.2MB array
    acc += w * T[p.x * 64 + lane];
  }
  float v = dis[n] * acc;
  int idx = n * 64 + lane;
  if (mode == 1) {
    float sv = v + skipA[idx];
    out[idx] = sv;
    outX1[idx] = sv;
  } else if (mode == 2) {
    float sv = v + skipA[idx] + skipX1[idx];
    out[idx] = sv > 0.f ? sv : 0.f;
  } else {
    out[idx] = v;
  }
}

// ---- global max pool over sorted batch (binary search bounds) ----
__global__ void k_pool(const float* __restrict__ x2, const int* __restrict__ batch, float* __restrict__ pooled) {
  int g = blockIdx.x;
  int c = threadIdx.x;  // 64 threads = 1 wave
  int lo = lowerb(batch, NN, g);
  int hi = lowerb(batch, NN, g + 1);
  float m = -INFINITY;
  for (int n = lo; n < hi; ++n) m = fmaxf(m, x2[n * 64 + c]);
  pooled[g * 64 + c] = m;
}

__global__ __launch_bounds__(256) void k_cls(const float* __restrict__ pooled, const float* __restrict__ lw,
                                             const float* __restrict__ lb, float* __restrict__ out) {
  int id = blockIdx.x * 256 + threadIdx.x;
  if (id >= NG * NCLS) return;
  int g = id / NCLS, k = id % NCLS;
  float acc = lb[k];
  #pragma unroll 8
  for (int c = 0; c < 64; ++c) acc += pooled[g * 64 + c] * lw[k * 64 + c];
  out[id] = acc;
}

extern "C" void kernel_launch(void* const* d_in, const int* in_sizes, int n_in,
                              void* d_out, int out_size, void* d_ws, size_t ws_size,
                              hipStream_t stream) {
  (void)in_sizes; (void)n_in; (void)out_size; (void)ws_size;
  const float* x     = (const float*)d_in[0];
  const int*   ei    = (const int*)d_in[1];
  const int*   batch = (const int*)d_in[2];
  // d_in[3] = dropout (0) -- unused
  const float* ea    = (const float*)d_in[4];
  const float* c1_lw = (const float*)d_in[5];
  const float* c1_w1 = (const float*)d_in[6];
  const float* c1_b1 = (const float*)d_in[7];
  const float* c1_w2 = (const float*)d_in[8];
  const float* c1_b2 = (const float*)d_in[9];
  const float* h1_lw = (const float*)d_in[10];
  const float* h1_w1 = (const float*)d_in[11];
  const float* h1_b1 = (const float*)d_in[12];
  const float* h1_w2 = (const float*)d_in[13];
  const float* h1_b2 = (const float*)d_in[14];
  const float* h2_lw = (const float*)d_in[15];
  const float* h2_w1 = (const float*)d_in[16];
  const float* h2_b1 = (const float*)d_in[17];
  const float* h2_w2 = (const float*)d_in[18];
  const float* h2_b2 = (const float*)d_in[19];
  const float* lin_w = (const float*)d_in[20];
  const float* lin_b = (const float*)d_in[21];
  float* out = (float*)d_out;

  char* base = (char*)d_ws;
  size_t off = 0;
  auto alloc = [&](size_t bytes) -> size_t {
    size_t o = off;
    off = (off + bytes + 255) & ~(size_t)255;
    return o;
  };
  size_t o_wcsr   = alloc((size_t)NCONV * NE * 4);
  size_t o_se     = alloc((size_t)NE * 8);
  size_t o_cptr   = alloc((size_t)(NN + 1) * 4);
  size_t o_cursor = alloc((size_t)NN * 4);         // zeroed region starts here
  size_t o_deg    = alloc((size_t)NCONV * NN * 4);
  size_t o_accum  = alloc((size_t)6 * 128 * 4);
  size_t o_lwt    = alloc((size_t)NCONV * 4096 * 4);  // zeroed region ends before here
  size_t o_T      = alloc((size_t)NN * 64 * 4);
  size_t o_A      = alloc((size_t)NN * 64 * 4);
  size_t o_B      = alloc((size_t)NN * 64 * 4);
  size_t o_X1     = alloc((size_t)NN * 64 * 4);
  size_t o_pool   = alloc((size_t)NG * 64 * 4);

  float* wcsr   = (float*)(base + o_wcsr);
  int2*  se     = (int2*)(base + o_se);
  int*   cptr   = (int*)(base + o_cptr);
  int*   cursor = (int*)(base + o_cursor);
  float* deg    = (float*)(base + o_deg);
  float* accum  = (float*)(base + o_accum);
  float* lwt    = (float*)(base + o_lwt);
  float* T      = (float*)(base + o_T);
  float* A      = (float*)(base + o_A);
  float* B      = (float*)(base + o_B);
  float* X1     = (float*)(base + o_X1);
  float* pooled = (float*)(base + o_pool);

  // one memset covers cursor + deg + accum (contiguous)
  hipMemsetAsync(base + o_cursor, 0, o_lwt - o_cursor, stream);

  const int* erow = ei;
  const int* ecol = ei + NE;

  k_hist<<<(NE + 255) / 256, 256, 0, stream>>>(ecol, cursor);
  k_scan<<<1, 1024, 0, stream>>>(cursor, cptr);
  k_scatter<<<(NE + 255) / 256, 256, 0, stream>>>(erow, ecol, cursor, se);

  MlpAll mw;
  mw.p[0] = {c1_w1, c1_b1, c1_w2, c1_b2};
  for (int i = 0; i < 3; ++i) {
    mw.p[1 + i] = {h1_w1 + i * 256, h1_b1 + i * 16, h1_w2 + i * 16, h1_b2 + i};
    mw.p[4 + i] = {h2_w1 + i * 256, h2_b1 + i * 16, h2_w2 + i * 16, h2_b2 + i};
  }
  k_mlp<<<(NE + 255) / 256, 256, 0, stream>>>(ecol, ea, wcsr, deg, mw);
  k_dis<<<(NCONV * NN + 255) / 256, 256, 0, stream>>>(deg);
  k_lwt<<<(NCONV * 4096) / 256, 256, 0, stream>>>(c1_lw, h1_lw, h2_lw, lwt);

  const int GB = (NN + 63) / 64;  // 782
  const int AB = (NN + 3) / 4;    // 12500

  // conv1 -> A (= x0)
  k_gemm<<<GB, 256, 0, stream>>>(x, lwt, nullptr, deg, T, 0);
  k_agg<<<AB, 256, 0, stream>>>(T, wcsr, se, cptr, deg, A, nullptr, nullptr, nullptr, 0);

  // hidden loop 1: x = conv(relu(BN(x))); after i==2 fuse x1 = x + x0
  for (int i = 0; i < 3; ++i) {
    const float* src = (i == 0) ? A : B;
    k_bnstat<<<256, 256, 0, stream>>>(src, accum + i * 128);
    k_gemm<<<GB, 256, 0, stream>>>(src, lwt + (1 + i) * 4096, accum + i * 128,
                                   deg + (size_t)(1 + i) * NN, T, 1);
    int mode = (i == 2) ? 1 : 0;
    k_agg<<<AB, 256, 0, stream>>>(T, wcsr + (size_t)(1 + i) * NE, se, cptr,
                                  deg + (size_t)(1 + i) * NN, B, A, nullptr, X1, mode);
  }
  // hidden loop 2; after i==2 fuse x2 = relu(x + x0 + x1)
  for (int i = 0; i < 3; ++i) {
    k_bnstat<<<256, 256, 0, stream>>>(B, accum + (3 + i) * 128);
    k_gemm<<<GB, 256, 0, stream>>>(B, lwt + (4 + i) * 4096, accum + (3 + i) * 128,
                                   deg + (size_t)(4 + i) * NN, T, 1);
    int mode = (i == 2) ? 2 : 0;
    k_agg<<<AB, 256, 0, stream>>>(T, wcsr + (size_t)(4 + i) * NE, se, cptr,
                                  deg + (size_t)(4 + i) * NN, B, A, X1, nullptr, mode);
  }

  k_pool<<<NG, 64, 0, stream>>>(B, batch, pooled);
  k_cls<<<(NG * NCLS + 255) / 256, 256, 0, stream>>>(pooled, lin_w, lin_b, out);
}

// Round 3
// 889.220 us; speedup vs baseline: 1.5127x; 1.5127x over previous
//
#include <hip/hip_runtime.h>
#include <hip/hip_bf16.h>
#include <math.h>

#define NN 50000
#define NE 800000
#define FE 16
#define CC 64
#define NG 512
#define NCLS 10
#define NCONV 7

struct MlpP { const float* w1; const float* b1; const float* w2; const float* b2; };
struct MlpAll { MlpP p[NCONV]; };

__device__ __forceinline__ int lowerb(const int* __restrict__ a, int n, int key) {
  int lo = 0, hi = n;
  while (lo < hi) { int m = (lo + hi) >> 1; if (a[m] < key) lo = m + 1; else hi = m; }
  return lo;
}

// ---- CSR build ----
__global__ __launch_bounds__(256) void k_hist(const int* __restrict__ ecol, int* __restrict__ cnt) {
  int e = blockIdx.x * 256 + threadIdx.x;
  if (e < NE) atomicAdd(&cnt[ecol[e]], 1);
}

__global__ __launch_bounds__(1024) void k_scan(int* __restrict__ cnt, int* __restrict__ cptr) {
  __shared__ int sc[1024];
  int t = threadIdx.x;
  const int CH = (NN + 1023) / 1024;  // 49
  int s0 = t * CH, s1 = s0 + CH;
  if (s0 > NN) s0 = NN;
  if (s1 > NN) s1 = NN;
  int sum = 0;
  for (int i = s0; i < s1; ++i) sum += cnt[i];
  sc[t] = sum;
  __syncthreads();
  for (int off = 1; off < 1024; off <<= 1) {
    int v = (t >= off) ? sc[t - off] : 0;
    __syncthreads();
    sc[t] += v;
    __syncthreads();
  }
  int run = sc[t] - sum;  // exclusive prefix
  for (int i = s0; i < s1; ++i) {
    int cv = cnt[i];
    cptr[i] = run;
    cnt[i] = run;  // becomes cursor
    run += cv;
  }
  if (t == 1023) cptr[NN] = sc[1023];
}

// ---- CSR scatter: csrc[p]=src (4B scatter, 3.2MB), pos[e]=p (coalesced) ----
__global__ __launch_bounds__(256) void k_scatter(
    const int* __restrict__ erow, const int* __restrict__ ecol,
    int* __restrict__ cursor, int* __restrict__ csrc, int* __restrict__ pos) {
  int e = blockIdx.x * 256 + threadIdx.x;
  if (e >= NE) return;
  int c = ecol[e];
  int p = atomicAdd(&cursor[c], 1);
  csrc[p] = erow[e];
  pos[e] = p;
}

// ---- all-7 edge MLPs: coalesced reads, ONE aligned 32B chunk scatter, NO atomics ----
__global__ __launch_bounds__(256) void k_mlp(
    const int* __restrict__ pos, const float* __restrict__ ea,
    float* __restrict__ wcsr8, MlpAll mw) {
  int e = blockIdx.x * 256 + threadIdx.x;
  if (e >= NE) return;
  float a[16];
  const float4* ea4 = reinterpret_cast<const float4*>(ea + (size_t)e * 16);
  float4 q0 = ea4[0], q1 = ea4[1], q2 = ea4[2], q3 = ea4[3];
  a[0]=q0.x; a[1]=q0.y; a[2]=q0.z; a[3]=q0.w;
  a[4]=q1.x; a[5]=q1.y; a[6]=q1.z; a[7]=q1.w;
  a[8]=q2.x; a[9]=q2.y; a[10]=q2.z; a[11]=q2.w;
  a[12]=q3.x; a[13]=q3.y; a[14]=q3.z; a[15]=q3.w;
  float wv[NCONV];
  #pragma unroll
  for (int j = 0; j < NCONV; ++j) {
    const float* w1 = mw.p[j].w1;
    const float* b1 = mw.p[j].b1;
    const float* w2 = mw.p[j].w2;
    float z = mw.p[j].b2[0];
    #pragma unroll
    for (int k = 0; k < 16; ++k) {
      float h = b1[k];
      #pragma unroll
      for (int m = 0; m < 16; ++m) h += a[m] * w1[k * 16 + m];
      h = h > 0.f ? h : 0.f;
      z += h * w2[k];
    }
    wv[j] = 1.f / (1.f + __expf(-z));
  }
  int p = pos[e];
  float4* dst = reinterpret_cast<float4*>(wcsr8 + (size_t)p * 8);
  dst[0] = make_float4(wv[0], wv[1], wv[2], wv[3]);
  dst[1] = make_float4(wv[4], wv[5], wv[6], 0.f);
}

// ---- deg per (node, conv) via CSR gather-sum; fused rsqrt -> dis ----
__global__ __launch_bounds__(256) void k_deg(const float* __restrict__ wcsr8,
                                             const int* __restrict__ cptr,
                                             float* __restrict__ dis) {
  int n = blockIdx.x * 256 + threadIdx.x;
  if (n >= NN) return;
  int lo = cptr[n], hi = cptr[n + 1];
  float s0=0,s1=0,s2=0,s3=0,s4=0,s5=0,s6=0;
  for (int k = lo; k < hi; ++k) {
    const float4* q = reinterpret_cast<const float4*>(wcsr8 + (size_t)k * 8);
    float4 a = q[0], b = q[1];
    s0+=a.x; s1+=a.y; s2+=a.z; s3+=a.w; s4+=b.x; s5+=b.y; s6+=b.z;
  }
  dis[0*NN+n]=rsqrtf(s0+1.f); dis[1*NN+n]=rsqrtf(s1+1.f); dis[2*NN+n]=rsqrtf(s2+1.f);
  dis[3*NN+n]=rsqrtf(s3+1.f); dis[4*NN+n]=rsqrtf(s4+1.f); dis[5*NN+n]=rsqrtf(s5+1.f);
  dis[6*NN+n]=rsqrtf(s6+1.f);
}

// transpose the 7 node-linear weights: lwT[j][ci][co] = lw_j[co][ci]
__global__ __launch_bounds__(256) void k_lwt(const float* __restrict__ c1, const float* __restrict__ h1,
                                             const float* __restrict__ h2, float* __restrict__ lwT) {
  int id = blockIdx.x * 256 + threadIdx.x;
  if (id >= NCONV * CC * CC) return;
  int j = id >> 12;
  int r = id & 4095;
  int co = r >> 6, ci = r & 63;
  const float* src = (j == 0) ? c1 : (j <= 3 ? h1 + (j - 1) * 4096 : h2 + (j - 4) * 4096);
  lwT[j * 4096 + ci * 64 + co] = src[co * 64 + ci];
}

// ---- BatchNorm stats: S and SS per channel ----
__global__ __launch_bounds__(256) void k_bnstat(const float* __restrict__ src, float* __restrict__ accum) {
  __shared__ float sS[256], sQ[256];
  int t = threadIdx.x;
  int c = t & 63, rg = t >> 6;
  int base = blockIdx.x * 196;
  float S = 0.f, Q = 0.f;
  for (int rr = rg; rr < 196; rr += 4) {
    int r = base + rr;
    if (r < NN) { float v = src[r * 64 + c]; S += v; Q += v * v; }
  }
  sS[t] = S; sQ[t] = Q;
  __syncthreads();
  if (t < 128) { sS[t] += sS[t + 128]; sQ[t] += sQ[t + 128]; }
  __syncthreads();
  if (t < 64) {
    atomicAdd(&accum[c], sS[t] + sS[t + 64]);
    atomicAdd(&accum[64 + c], sQ[t] + sQ[t + 64]);
  }
}

// ---- fused (BN+ReLU)? -> GEMM -> *dis : dst = f(src) @ lwT * dis[n] ----
__global__ __launch_bounds__(256) void k_gemm(const float* __restrict__ src, const float* __restrict__ lwT,
                                              const float* __restrict__ accum, const float* __restrict__ dis,
                                              float* __restrict__ dst, int useBN) {
  __shared__ float xs[64 * 65];
  int t = threadIdx.x;
  int rows0 = blockIdx.x * 64;
  // stage 64 rows (float4), fused BN+ReLU
  for (int i = 0; i < 4; ++i) {
    int f = t + i * 256;            // float4 index in [0,1024)
    int r = f >> 4, c4 = (f & 15) * 4;
    int row = rows0 + r;
    float4 v = make_float4(0.f, 0.f, 0.f, 0.f);
    if (row < NN) v = *reinterpret_cast<const float4*>(src + (size_t)row * 64 + c4);
    if (useBN) {
      float4 S = *reinterpret_cast<const float4*>(accum + c4);
      float4 Q = *reinterpret_cast<const float4*>(accum + 64 + c4);
      float mu, var, rs;
      mu = S.x * (1.0f/NN); var = Q.x*(1.0f/NN)-mu*mu; var = var<0.f?0.f:var; rs = rsqrtf(var+1e-5f);
      v.x = (v.x-mu)*rs; v.x = v.x>0.f?v.x:0.f;
      mu = S.y * (1.0f/NN); var = Q.y*(1.0f/NN)-mu*mu; var = var<0.f?0.f:var; rs = rsqrtf(var+1e-5f);
      v.y = (v.y-mu)*rs; v.y = v.y>0.f?v.y:0.f;
      mu = S.z * (1.0f/NN); var = Q.z*(1.0f/NN)-mu*mu; var = var<0.f?0.f:var; rs = rsqrtf(var+1e-5f);
      v.z = (v.z-mu)*rs; v.z = v.z>0.f?v.z:0.f;
      mu = S.w * (1.0f/NN); var = Q.w*(1.0f/NN)-mu*mu; var = var<0.f?0.f:var; rs = rsqrtf(var+1e-5f);
      v.w = (v.w-mu)*rs; v.w = v.w>0.f?v.w:0.f;
    }
    xs[r * 65 + c4 + 0] = v.x;
    xs[r * 65 + c4 + 1] = v.y;
    xs[r * 65 + c4 + 2] = v.z;
    xs[r * 65 + c4 + 3] = v.w;
  }
  __syncthreads();
  int lane = t & 63;
  int cobase = __builtin_amdgcn_readfirstlane((t >> 6) << 4);  // wave-uniform -> scalar weight loads
  float acc[16];
  #pragma unroll
  for (int u = 0; u < 16; ++u) acc[u] = 0.f;
  #pragma unroll 8
  for (int ci = 0; ci < 64; ++ci) {
    float xv = xs[lane * 65 + ci];
    const float* wrow = lwT + ci * 64 + cobase;
    #pragma unroll
    for (int u = 0; u < 16; ++u) acc[u] += xv * wrow[u];
  }
  __syncthreads();
  int row = rows0 + lane;
  float d = (row < NN) ? dis[row] : 0.f;
  #pragma unroll
  for (int u = 0; u < 16; ++u) xs[lane * 65 + cobase + u] = acc[u] * d;
  __syncthreads();
  for (int i = 0; i < 4; ++i) {
    int f = t + i * 256;
    int r = f >> 4, c4 = (f & 15) * 4;
    int orow = rows0 + r;
    if (orow < NN) {
      float4 v = make_float4(xs[r*65+c4], xs[r*65+c4+1], xs[r*65+c4+2], xs[r*65+c4+3]);
      *reinterpret_cast<float4*>(dst + (size_t)orow * 64 + c4) = v;
    }
  }
}

// ---- aggregation: wave per node, lane = channel; w in CSR order (stride 8) ----
// mode 0: out = v ; mode 1: s=v+skipA -> out=s, outX1=s ; mode 2: out = relu(v+skipA+skipX1)
__global__ __launch_bounds__(256) void k_agg(const float* __restrict__ T, const float* __restrict__ wj,
                                             const int* __restrict__ csrc, const int* __restrict__ cptr,
                                             const float* __restrict__ dis, float* __restrict__ out,
                                             const float* __restrict__ skipA, const float* __restrict__ skipX1,
                                             float* __restrict__ outX1, int mode) {
  int t = threadIdx.x;
  int n = blockIdx.x * 4 + (t >> 6);
  if (n >= NN) return;
  int lane = t & 63;
  int lo = cptr[n], hi = cptr[n + 1];
  float acc = T[(size_t)n * 64 + lane];  // self loop (dis[n] folded into T)
  int k = lo;
  for (; k + 1 < hi; k += 2) {
    int s0 = csrc[k], s1 = csrc[k + 1];
    float w0 = wj[(size_t)k * 8], w1 = wj[(size_t)(k + 1) * 8];
    acc += w0 * T[(size_t)s0 * 64 + lane];
    acc += w1 * T[(size_t)s1 * 64 + lane];
  }
  if (k < hi) {
    int s0 = csrc[k];
    float w0 = wj[(size_t)k * 8];
    acc += w0 * T[(size_t)s0 * 64 + lane];
  }
  float v = dis[n] * acc;
  size_t idx = (size_t)n * 64 + lane;
  if (mode == 1) {
    float sv = v + skipA[idx];
    out[idx] = sv;
    outX1[idx] = sv;
  } else if (mode == 2) {
    float sv = v + skipA[idx] + skipX1[idx];
    out[idx] = sv > 0.f ? sv : 0.f;
  } else {
    out[idx] = v;
  }
}

// ---- global max pool over sorted batch (binary search bounds) ----
__global__ void k_pool(const float* __restrict__ x2, const int* __restrict__ batch, float* __restrict__ pooled) {
  int g = blockIdx.x;
  int c = threadIdx.x;  // 64 threads = 1 wave
  int lo = lowerb(batch, NN, g);
  int hi = lowerb(batch, NN, g + 1);
  float m = -INFINITY;
  for (int n = lo; n < hi; ++n) m = fmaxf(m, x2[(size_t)n * 64 + c]);
  pooled[g * 64 + c] = m;
}

__global__ __launch_bounds__(256) void k_cls(const float* __restrict__ pooled, const float* __restrict__ lw,
                                             const float* __restrict__ lb, float* __restrict__ out) {
  int id = blockIdx.x * 256 + threadIdx.x;
  if (id >= NG * NCLS) return;
  int g = id / NCLS, k = id % NCLS;
  float acc = lb[k];
  #pragma unroll 8
  for (int c = 0; c < 64; ++c) acc += pooled[g * 64 + c] * lw[k * 64 + c];
  out[id] = acc;
}

extern "C" void kernel_launch(void* const* d_in, const int* in_sizes, int n_in,
                              void* d_out, int out_size, void* d_ws, size_t ws_size,
                              hipStream_t stream) {
  (void)in_sizes; (void)n_in; (void)out_size; (void)ws_size;
  const float* x     = (const float*)d_in[0];
  const int*   ei    = (const int*)d_in[1];
  const int*   batch = (const int*)d_in[2];
  // d_in[3] = dropout (0) -- unused
  const float* ea    = (const float*)d_in[4];
  const float* c1_lw = (const float*)d_in[5];
  const float* c1_w1 = (const float*)d_in[6];
  const float* c1_b1 = (const float*)d_in[7];
  const float* c1_w2 = (const float*)d_in[8];
  const float* c1_b2 = (const float*)d_in[9];
  const float* h1_lw = (const float*)d_in[10];
  const float* h1_w1 = (const float*)d_in[11];
  const float* h1_b1 = (const float*)d_in[12];
  const float* h1_w2 = (const float*)d_in[13];
  const float* h1_b2 = (const float*)d_in[14];
  const float* h2_lw = (const float*)d_in[15];
  const float* h2_w1 = (const float*)d_in[16];
  const float* h2_b1 = (const float*)d_in[17];
  const float* h2_w2 = (const float*)d_in[18];
  const float* h2_b2 = (const float*)d_in[19];
  const float* lin_w = (const float*)d_in[20];
  const float* lin_b = (const float*)d_in[21];
  float* out = (float*)d_out;

  char* base = (char*)d_ws;
  size_t off = 0;
  auto alloc = [&](size_t bytes) -> size_t {
    size_t o = off;
    off = (off + bytes + 255) & ~(size_t)255;
    return o;
  };
  size_t o_wcsr8  = alloc((size_t)NE * 8 * 4);        // 25.6MB, CSR order, 8 floats/edge
  size_t o_csrc   = alloc((size_t)NE * 4);
  size_t o_pos    = alloc((size_t)NE * 4);
  size_t o_cptr   = alloc((size_t)(NN + 1) * 4);
  size_t o_cursor = alloc((size_t)NN * 4);            // zeroed region starts here
  size_t o_accum  = alloc((size_t)6 * 128 * 4);       // zeroed region ends after this
  size_t o_dis    = alloc((size_t)NCONV * NN * 4);
  size_t o_lwt    = alloc((size_t)NCONV * 4096 * 4);
  size_t o_T      = alloc((size_t)NN * 64 * 4);
  size_t o_A      = alloc((size_t)NN * 64 * 4);
  size_t o_B      = alloc((size_t)NN * 64 * 4);
  size_t o_X1     = alloc((size_t)NN * 64 * 4);
  size_t o_pool   = alloc((size_t)NG * 64 * 4);

  float* wcsr8  = (float*)(base + o_wcsr8);
  int*   csrc   = (int*)(base + o_csrc);
  int*   pos    = (int*)(base + o_pos);
  int*   cptr   = (int*)(base + o_cptr);
  int*   cursor = (int*)(base + o_cursor);
  float* accum  = (float*)(base + o_accum);
  float* dis    = (float*)(base + o_dis);
  float* lwt    = (float*)(base + o_lwt);
  float* T      = (float*)(base + o_T);
  float* A      = (float*)(base + o_A);
  float* B      = (float*)(base + o_B);
  float* X1     = (float*)(base + o_X1);
  float* pooled = (float*)(base + o_pool);

  // one memset covers cursor + accum (contiguous)
  hipMemsetAsync(base + o_cursor, 0, o_dis - o_cursor, stream);

  const int* erow = ei;
  const int* ecol = ei + NE;

  k_hist<<<(NE + 255) / 256, 256, 0, stream>>>(ecol, cursor);
  k_scan<<<1, 1024, 0, stream>>>(cursor, cptr);
  k_scatter<<<(NE + 255) / 256, 256, 0, stream>>>(erow, ecol, cursor, csrc, pos);

  MlpAll mw;
  mw.p[0] = {c1_w1, c1_b1, c1_w2, c1_b2};
  for (int i = 0; i < 3; ++i) {
    mw.p[1 + i] = {h1_w1 + i * 256, h1_b1 + i * 16, h1_w2 + i * 16, h1_b2 + i};
    mw.p[4 + i] = {h2_w1 + i * 256, h2_b1 + i * 16, h2_w2 + i * 16, h2_b2 + i};
  }
  k_mlp<<<(NE + 255) / 256, 256, 0, stream>>>(pos, ea, wcsr8, mw);
  k_deg<<<(NN + 255) / 256, 256, 0, stream>>>(wcsr8, cptr, dis);
  k_lwt<<<(NCONV * 4096) / 256, 256, 0, stream>>>(c1_lw, h1_lw, h2_lw, lwt);

  const int GB = (NN + 63) / 64;  // 782
  const int AB = (NN + 3) / 4;    // 12500

  // conv1 -> A (= x0)
  k_gemm<<<GB, 256, 0, stream>>>(x, lwt, nullptr, dis, T, 0);
  k_agg<<<AB, 256, 0, stream>>>(T, wcsr8 + 0, csrc, cptr, dis, A, nullptr, nullptr, nullptr, 0);

  // hidden loop 1: x = conv(relu(BN(x))); after i==2 fuse x1 = x + x0
  for (int i = 0; i < 3; ++i) {
    const float* src = (i == 0) ? A : B;
    k_bnstat<<<256, 256, 0, stream>>>(src, accum + i * 128);
    k_gemm<<<GB, 256, 0, stream>>>(src, lwt + (1 + i) * 4096, accum + i * 128,
                                   dis + (size_t)(1 + i) * NN, T, 1);
    int mode = (i == 2) ? 1 : 0;
    k_agg<<<AB, 256, 0, stream>>>(T, wcsr8 + (1 + i), csrc, cptr,
                                  dis + (size_t)(1 + i) * NN, B, A, nullptr, X1, mode);
  }
  // hidden loop 2; after i==2 fuse x2 = relu(x + x0 + x1)
  for (int i = 0; i < 3; ++i) {
    k_bnstat<<<256, 256, 0, stream>>>(B, accum + (3 + i) * 128);
    k_gemm<<<GB, 256, 0, stream>>>(B, lwt + (4 + i) * 4096, accum + (3 + i) * 128,
                                   dis + (size_t)(4 + i) * NN, T, 1);
    int mode = (i == 2) ? 2 : 0;
    k_agg<<<AB, 256, 0, stream>>>(T, wcsr8 + (4 + i), csrc, cptr,
                                  dis + (size_t)(4 + i) * NN, B, A, X1, nullptr, mode);
  }

  k_pool<<<NG, 64, 0, stream>>>(B, batch, pooled);
  k_cls<<<(NG * NCLS + 255) / 256, 256, 0, stream>>>(pooled, lin_w, lin_b, out);
}

// Round 4
// 702.662 us; speedup vs baseline: 1.9143x; 1.2655x over previous
//
#include <hip/hip_runtime.h>
#include <hip/hip_bf16.h>
#include <math.h>

#define NN 50000
#define NE 800000
#define FE 16
#define CC 64
#define NG 512
#define NCLS 10
#define NCONV 7
#define SCAN_B 49  // ceil(NN/1024)

struct MlpP { const float* w1; const float* b1; const float* w2; const float* b2; };
struct MlpAll { MlpP p[NCONV]; };

__device__ __forceinline__ int lowerb(const int* __restrict__ a, int n, int key) {
  int lo = 0, hi = n;
  while (lo < hi) { int m = (lo + hi) >> 1; if (a[m] < key) lo = m + 1; else hi = m; }
  return lo;
}

// ---- CSR build ----
__global__ __launch_bounds__(256) void k_hist(const int* __restrict__ ecol, int* __restrict__ cnt) {
  int e = blockIdx.x * 256 + threadIdx.x;
  if (e < NE) atomicAdd(&cnt[ecol[e]], 1);
}

// 3-phase parallel scan of cnt[NN] -> cptr (exclusive), cursor init
__global__ __launch_bounds__(1024) void k_scanA(const int* __restrict__ cnt, int* __restrict__ excl,
                                                int* __restrict__ bsum) {
  __shared__ int sc[1024];
  int t = threadIdx.x;
  int i = blockIdx.x * 1024 + t;
  int v = (i < NN) ? cnt[i] : 0;
  sc[t] = v;
  __syncthreads();
  for (int off = 1; off < 1024; off <<= 1) {
    int u = (t >= off) ? sc[t - off] : 0;
    __syncthreads();
    sc[t] += u;
    __syncthreads();
  }
  if (i < NN) excl[i] = sc[t] - v;
  if (t == 1023) bsum[blockIdx.x] = sc[1023];
}

__global__ void k_scanB(const int* __restrict__ bsum, int* __restrict__ boff) {
  int lane = threadIdx.x;  // 64 threads = 1 wave
  int v = (lane < SCAN_B) ? bsum[lane] : 0;
  int own = v;
  for (int off = 1; off < 64; off <<= 1) {
    int u = __shfl_up(v, off);
    if (lane >= off) v += u;
  }
  if (lane < SCAN_B) boff[lane] = v - own;  // exclusive block offset
}

__global__ __launch_bounds__(1024) void k_scanC(const int* __restrict__ excl, const int* __restrict__ boff,
                                                int* __restrict__ cptr, int* __restrict__ cursor) {
  int i = blockIdx.x * 1024 + threadIdx.x;
  if (i < NN) {
    int p = excl[i] + boff[blockIdx.x];
    cptr[i] = p;
    cursor[i] = p;
  }
  if (i == 0) cptr[NN] = NE;
}

// ---- CSR scatter: csrc[p]=src (4B scatter, 3.2MB), pos[e]=p (coalesced) ----
__global__ __launch_bounds__(256) void k_scatter(
    const int* __restrict__ erow, const int* __restrict__ ecol,
    int* __restrict__ cursor, int* __restrict__ csrc, int* __restrict__ pos) {
  int e = blockIdx.x * 256 + threadIdx.x;
  if (e >= NE) return;
  int c = ecol[e];
  int p = atomicAdd(&cursor[c], 1);
  csrc[p] = erow[e];
  pos[e] = p;
}

// ---- all-7 edge MLPs: coalesced reads, ONE aligned 32B chunk scatter, NO atomics ----
__global__ __launch_bounds__(256) void k_mlp(
    const int* __restrict__ pos, const float* __restrict__ ea,
    float* __restrict__ wcsr8, MlpAll mw) {
  int e = blockIdx.x * 256 + threadIdx.x;
  if (e >= NE) return;
  float a[16];
  const float4* ea4 = reinterpret_cast<const float4*>(ea + (size_t)e * 16);
  float4 q0 = ea4[0], q1 = ea4[1], q2 = ea4[2], q3 = ea4[3];
  a[0]=q0.x; a[1]=q0.y; a[2]=q0.z; a[3]=q0.w;
  a[4]=q1.x; a[5]=q1.y; a[6]=q1.z; a[7]=q1.w;
  a[8]=q2.x; a[9]=q2.y; a[10]=q2.z; a[11]=q2.w;
  a[12]=q3.x; a[13]=q3.y; a[14]=q3.z; a[15]=q3.w;
  float wv[NCONV];
  #pragma unroll
  for (int j = 0; j < NCONV; ++j) {
    const float* w1 = mw.p[j].w1;
    const float* b1 = mw.p[j].b1;
    const float* w2 = mw.p[j].w2;
    float z = mw.p[j].b2[0];
    #pragma unroll
    for (int k = 0; k < 16; ++k) {
      float h = b1[k];
      #pragma unroll
      for (int m = 0; m < 16; ++m) h += a[m] * w1[k * 16 + m];
      h = h > 0.f ? h : 0.f;
      z += h * w2[k];
    }
    wv[j] = 1.f / (1.f + __expf(-z));
  }
  int p = pos[e];
  float4* dst = reinterpret_cast<float4*>(wcsr8 + (size_t)p * 8);
  dst[0] = make_float4(wv[0], wv[1], wv[2], wv[3]);
  dst[1] = make_float4(wv[4], wv[5], wv[6], 0.f);
}

// ---- deg per (node, conv) via CSR gather-sum; fused rsqrt -> dis ----
__global__ __launch_bounds__(256) void k_deg(const float* __restrict__ wcsr8,
                                             const int* __restrict__ cptr,
                                             float* __restrict__ dis) {
  int n = blockIdx.x * 256 + threadIdx.x;
  if (n >= NN) return;
  int lo = cptr[n], hi = cptr[n + 1];
  float s0=0,s1=0,s2=0,s3=0,s4=0,s5=0,s6=0;
  for (int k = lo; k < hi; ++k) {
    const float4* q = reinterpret_cast<const float4*>(wcsr8 + (size_t)k * 8);
    float4 a = q[0], b = q[1];
    s0+=a.x; s1+=a.y; s2+=a.z; s3+=a.w; s4+=b.x; s5+=b.y; s6+=b.z;
  }
  dis[0*NN+n]=rsqrtf(s0+1.f); dis[1*NN+n]=rsqrtf(s1+1.f); dis[2*NN+n]=rsqrtf(s2+1.f);
  dis[3*NN+n]=rsqrtf(s3+1.f); dis[4*NN+n]=rsqrtf(s4+1.f); dis[5*NN+n]=rsqrtf(s5+1.f);
  dis[6*NN+n]=rsqrtf(s6+1.f);
}

// transpose the 7 node-linear weights: lwT[j][ci][co] = lw_j[co][ci]
__global__ __launch_bounds__(256) void k_lwt(const float* __restrict__ c1, const float* __restrict__ h1,
                                             const float* __restrict__ h2, float* __restrict__ lwT) {
  int id = blockIdx.x * 256 + threadIdx.x;
  if (id >= NCONV * CC * CC) return;
  int j = id >> 12;
  int r = id & 4095;
  int co = r >> 6, ci = r & 63;
  const float* src = (j == 0) ? c1 : (j <= 3 ? h1 + (j - 1) * 4096 : h2 + (j - 4) * 4096);
  lwT[j * 4096 + ci * 64 + co] = src[co * 64 + ci];
}

// ---- BatchNorm stats: S and SS per channel ----
__global__ __launch_bounds__(256) void k_bnstat(const float* __restrict__ src, float* __restrict__ accum) {
  __shared__ float sS[256], sQ[256];
  int t = threadIdx.x;
  int c = t & 63, rg = t >> 6;
  int base = blockIdx.x * 196;
  float S = 0.f, Q = 0.f;
  for (int rr = rg; rr < 196; rr += 4) {
    int r = base + rr;
    if (r < NN) { float v = src[r * 64 + c]; S += v; Q += v * v; }
  }
  sS[t] = S; sQ[t] = Q;
  __syncthreads();
  if (t < 128) { sS[t] += sS[t + 128]; sQ[t] += sQ[t + 128]; }
  __syncthreads();
  if (t < 64) {
    atomicAdd(&accum[c], sS[t] + sS[t + 64]);
    atomicAdd(&accum[64 + c], sQ[t] + sQ[t + 64]);
  }
}

// ---- fused (BN+ReLU)? -> GEMM -> *dis : dst = f(src) @ lwT * dis[n] ----
__global__ __launch_bounds__(256) void k_gemm(const float* __restrict__ src, const float* __restrict__ lwT,
                                              const float* __restrict__ accum, const float* __restrict__ dis,
                                              float* __restrict__ dst, int useBN) {
  __shared__ float xs[64 * 65];
  int t = threadIdx.x;
  int rows0 = blockIdx.x * 64;
  // stage 64 rows (float4), fused BN+ReLU
  for (int i = 0; i < 4; ++i) {
    int f = t + i * 256;            // float4 index in [0,1024)
    int r = f >> 4, c4 = (f & 15) * 4;
    int row = rows0 + r;
    float4 v = make_float4(0.f, 0.f, 0.f, 0.f);
    if (row < NN) v = *reinterpret_cast<const float4*>(src + (size_t)row * 64 + c4);
    if (useBN) {
      float4 S = *reinterpret_cast<const float4*>(accum + c4);
      float4 Q = *reinterpret_cast<const float4*>(accum + 64 + c4);
      float mu, var, rs;
      mu = S.x * (1.0f/NN); var = Q.x*(1.0f/NN)-mu*mu; var = var<0.f?0.f:var; rs = rsqrtf(var+1e-5f);
      v.x = (v.x-mu)*rs; v.x = v.x>0.f?v.x:0.f;
      mu = S.y * (1.0f/NN); var = Q.y*(1.0f/NN)-mu*mu; var = var<0.f?0.f:var; rs = rsqrtf(var+1e-5f);
      v.y = (v.y-mu)*rs; v.y = v.y>0.f?v.y:0.f;
      mu = S.z * (1.0f/NN); var = Q.z*(1.0f/NN)-mu*mu; var = var<0.f?0.f:var; rs = rsqrtf(var+1e-5f);
      v.z = (v.z-mu)*rs; v.z = v.z>0.f?v.z:0.f;
      mu = S.w * (1.0f/NN); var = Q.w*(1.0f/NN)-mu*mu; var = var<0.f?0.f:var; rs = rsqrtf(var+1e-5f);
      v.w = (v.w-mu)*rs; v.w = v.w>0.f?v.w:0.f;
    }
    xs[r * 65 + c4 + 0] = v.x;
    xs[r * 65 + c4 + 1] = v.y;
    xs[r * 65 + c4 + 2] = v.z;
    xs[r * 65 + c4 + 3] = v.w;
  }
  __syncthreads();
  int lane = t & 63;
  int cobase = __builtin_amdgcn_readfirstlane((t >> 6) << 4);  // wave-uniform -> scalar weight loads
  float acc[16];
  #pragma unroll
  for (int u = 0; u < 16; ++u) acc[u] = 0.f;
  #pragma unroll 8
  for (int ci = 0; ci < 64; ++ci) {
    float xv = xs[lane * 65 + ci];
    const float* wrow = lwT + ci * 64 + cobase;
    #pragma unroll
    for (int u = 0; u < 16; ++u) acc[u] += xv * wrow[u];
  }
  __syncthreads();
  int row = rows0 + lane;
  float d = (row < NN) ? dis[row] : 0.f;
  #pragma unroll
  for (int u = 0; u < 16; ++u) xs[lane * 65 + cobase + u] = acc[u] * d;
  __syncthreads();
  for (int i = 0; i < 4; ++i) {
    int f = t + i * 256;
    int r = f >> 4, c4 = (f & 15) * 4;
    int orow = rows0 + r;
    if (orow < NN) {
      float4 v = make_float4(xs[r*65+c4], xs[r*65+c4+1], xs[r*65+c4+2], xs[r*65+c4+3]);
      *reinterpret_cast<float4*>(dst + (size_t)orow * 64 + c4) = v;
    }
  }
}

// ---- aggregation: wave per node, lane = channel; w in CSR order (stride 8) ----
// mode 0: out = v ; mode 1: s=v+skipA -> out=s, outX1=s ; mode 2: out = relu(v+skipA+skipX1)
__global__ __launch_bounds__(256) void k_agg(const float* __restrict__ T, const float* __restrict__ wj,
                                             const int* __restrict__ csrc, const int* __restrict__ cptr,
                                             const float* __restrict__ dis, float* __restrict__ out,
                                             const float* __restrict__ skipA, const float* __restrict__ skipX1,
                                             float* __restrict__ outX1, int mode) {
  int t = threadIdx.x;
  int n = blockIdx.x * 4 + (t >> 6);
  if (n >= NN) return;
  int lane = t & 63;
  int lo = cptr[n], hi = cptr[n + 1];
  float acc = T[(size_t)n * 64 + lane];  // self loop (dis[n] folded into T)
  int k = lo;
  for (; k + 3 < hi; k += 4) {
    int s0 = csrc[k], s1 = csrc[k + 1], s2 = csrc[k + 2], s3 = csrc[k + 3];
    float w0 = wj[(size_t)k * 8],       w1 = wj[(size_t)(k + 1) * 8];
    float w2 = wj[(size_t)(k + 2) * 8], w3 = wj[(size_t)(k + 3) * 8];
    float t0 = T[(size_t)s0 * 64 + lane], t1 = T[(size_t)s1 * 64 + lane];
    float t2 = T[(size_t)s2 * 64 + lane], t3 = T[(size_t)s3 * 64 + lane];
    acc += w0 * t0; acc += w1 * t1; acc += w2 * t2; acc += w3 * t3;
  }
  for (; k < hi; ++k) {
    int s0 = csrc[k];
    float w0 = wj[(size_t)k * 8];
    acc += w0 * T[(size_t)s0 * 64 + lane];
  }
  float v = dis[n] * acc;
  size_t idx = (size_t)n * 64 + lane;
  if (mode == 1) {
    float sv = v + skipA[idx];
    out[idx] = sv;
    outX1[idx] = sv;
  } else if (mode == 2) {
    float sv = v + skipA[idx] + skipX1[idx];
    out[idx] = sv > 0.f ? sv : 0.f;
  } else {
    out[idx] = v;
  }
}

// ---- global max pool over sorted batch (binary search bounds) ----
__global__ void k_pool(const float* __restrict__ x2, const int* __restrict__ batch, float* __restrict__ pooled) {
  int g = blockIdx.x;
  int c = threadIdx.x;  // 64 threads = 1 wave
  int lo = lowerb(batch, NN, g);
  int hi = lowerb(batch, NN, g + 1);
  float m = -INFINITY;
  for (int n = lo; n < hi; ++n) m = fmaxf(m, x2[(size_t)n * 64 + c]);
  pooled[g * 64 + c] = m;
}

__global__ __launch_bounds__(256) void k_cls(const float* __restrict__ pooled, const float* __restrict__ lw,
                                             const float* __restrict__ lb, float* __restrict__ out) {
  int id = blockIdx.x * 256 + threadIdx.x;
  if (id >= NG * NCLS) return;
  int g = id / NCLS, k = id % NCLS;
  float acc = lb[k];
  #pragma unroll 8
  for (int c = 0; c < 64; ++c) acc += pooled[g * 64 + c] * lw[k * 64 + c];
  out[id] = acc;
}

extern "C" void kernel_launch(void* const* d_in, const int* in_sizes, int n_in,
                              void* d_out, int out_size, void* d_ws, size_t ws_size,
                              hipStream_t stream) {
  (void)in_sizes; (void)n_in; (void)out_size; (void)ws_size;
  const float* x     = (const float*)d_in[0];
  const int*   ei    = (const int*)d_in[1];
  const int*   batch = (const int*)d_in[2];
  // d_in[3] = dropout (0) -- unused
  const float* ea    = (const float*)d_in[4];
  const float* c1_lw = (const float*)d_in[5];
  const float* c1_w1 = (const float*)d_in[6];
  const float* c1_b1 = (const float*)d_in[7];
  const float* c1_w2 = (const float*)d_in[8];
  const float* c1_b2 = (const float*)d_in[9];
  const float* h1_lw = (const float*)d_in[10];
  const float* h1_w1 = (const float*)d_in[11];
  const float* h1_b1 = (const float*)d_in[12];
  const float* h1_w2 = (const float*)d_in[13];
  const float* h1_b2 = (const float*)d_in[14];
  const float* h2_lw = (const float*)d_in[15];
  const float* h2_w1 = (const float*)d_in[16];
  const float* h2_b1 = (const float*)d_in[17];
  const float* h2_w2 = (const float*)d_in[18];
  const float* h2_b2 = (const float*)d_in[19];
  const float* lin_w = (const float*)d_in[20];
  const float* lin_b = (const float*)d_in[21];
  float* out = (float*)d_out;

  char* base = (char*)d_ws;
  size_t off = 0;
  auto alloc = [&](size_t bytes) -> size_t {
    size_t o = off;
    off = (off + bytes + 255) & ~(size_t)255;
    return o;
  };
  size_t o_wcsr8  = alloc((size_t)NE * 8 * 4);        // 25.6MB, CSR order, 8 floats/edge
  size_t o_csrc   = alloc((size_t)NE * 4);
  size_t o_pos    = alloc((size_t)NE * 4);
  size_t o_cptr   = alloc((size_t)(NN + 1) * 4);
  size_t o_excl   = alloc((size_t)NN * 4);
  size_t o_bsum   = alloc((size_t)64 * 4);
  size_t o_boff   = alloc((size_t)64 * 4);
  size_t o_cnt    = alloc((size_t)NN * 4);            // zeroed region starts here (cnt -> cursor)
  size_t o_accum  = alloc((size_t)6 * 128 * 4);       // zeroed region ends after this
  size_t o_dis    = alloc((size_t)NCONV * NN * 4);
  size_t o_lwt    = alloc((size_t)NCONV * 4096 * 4);
  size_t o_T      = alloc((size_t)NN * 64 * 4);
  size_t o_A      = alloc((size_t)NN * 64 * 4);
  size_t o_B      = alloc((size_t)NN * 64 * 4);
  size_t o_X1     = alloc((size_t)NN * 64 * 4);
  size_t o_pool   = alloc((size_t)NG * 64 * 4);

  float* wcsr8  = (float*)(base + o_wcsr8);
  int*   csrc   = (int*)(base + o_csrc);
  int*   pos    = (int*)(base + o_pos);
  int*   cptr   = (int*)(base + o_cptr);
  int*   excl   = (int*)(base + o_excl);
  int*   bsum   = (int*)(base + o_bsum);
  int*   boff   = (int*)(base + o_boff);
  int*   cnt    = (int*)(base + o_cnt);   // doubles as cursor after scanC
  float* accum  = (float*)(base + o_accum);
  float* dis    = (float*)(base + o_dis);
  float* lwt    = (float*)(base + o_lwt);
  float* T      = (float*)(base + o_T);
  float* A      = (float*)(base + o_A);
  float* B      = (float*)(base + o_B);
  float* X1     = (float*)(base + o_X1);
  float* pooled = (float*)(base + o_pool);

  // one memset covers cnt + accum (contiguous)
  hipMemsetAsync(base + o_cnt, 0, o_dis - o_cnt, stream);

  const int* erow = ei;
  const int* ecol = ei + NE;

  k_hist<<<(NE + 255) / 256, 256, 0, stream>>>(ecol, cnt);
  k_scanA<<<SCAN_B, 1024, 0, stream>>>(cnt, excl, bsum);
  k_scanB<<<1, 64, 0, stream>>>(bsum, boff);
  k_scanC<<<SCAN_B, 1024, 0, stream>>>(excl, boff, cptr, cnt);
  k_scatter<<<(NE + 255) / 256, 256, 0, stream>>>(erow, ecol, cnt, csrc, pos);

  MlpAll mw;
  mw.p[0] = {c1_w1, c1_b1, c1_w2, c1_b2};
  for (int i = 0; i < 3; ++i) {
    mw.p[1 + i] = {h1_w1 + i * 256, h1_b1 + i * 16, h1_w2 + i * 16, h1_b2 + i};
    mw.p[4 + i] = {h2_w1 + i * 256, h2_b1 + i * 16, h2_w2 + i * 16, h2_b2 + i};
  }
  k_mlp<<<(NE + 255) / 256, 256, 0, stream>>>(pos, ea, wcsr8, mw);
  k_deg<<<(NN + 255) / 256, 256, 0, stream>>>(wcsr8, cptr, dis);
  k_lwt<<<(NCONV * 4096) / 256, 256, 0, stream>>>(c1_lw, h1_lw, h2_lw, lwt);

  const int GB = (NN + 63) / 64;  // 782
  const int AB = (NN + 3) / 4;    // 12500

  // conv1 -> A (= x0)
  k_gemm<<<GB, 256, 0, stream>>>(x, lwt, nullptr, dis, T, 0);
  k_agg<<<AB, 256, 0, stream>>>(T, wcsr8 + 0, csrc, cptr, dis, A, nullptr, nullptr, nullptr, 0);

  // hidden loop 1: x = conv(relu(BN(x))); after i==2 fuse x1 = x + x0
  for (int i = 0; i < 3; ++i) {
    const float* src = (i == 0) ? A : B;
    k_bnstat<<<256, 256, 0, stream>>>(src, accum + i * 128);
    k_gemm<<<GB, 256, 0, stream>>>(src, lwt + (1 + i) * 4096, accum + i * 128,
                                   dis + (size_t)(1 + i) * NN, T, 1);
    int mode = (i == 2) ? 1 : 0;
    k_agg<<<AB, 256, 0, stream>>>(T, wcsr8 + (1 + i), csrc, cptr,
                                  dis + (size_t)(1 + i) * NN, B, A, nullptr, X1, mode);
  }
  // hidden loop 2; after i==2 fuse x2 = relu(x + x0 + x1)
  for (int i = 0; i < 3; ++i) {
    k_bnstat<<<256, 256, 0, stream>>>(B, accum + (3 + i) * 128);
    k_gemm<<<GB, 256, 0, stream>>>(B, lwt + (4 + i) * 4096, accum + (3 + i) * 128,
                                   dis + (size_t)(4 + i) * NN, T, 1);
    int mode = (i == 2) ? 2 : 0;
    k_agg<<<AB, 256, 0, stream>>>(T, wcsr8 + (4 + i), csrc, cptr,
                                  dis + (size_t)(4 + i) * NN, B, A, X1, nullptr, mode);
  }

  k_pool<<<NG, 64, 0, stream>>>(B, batch, pooled);
  k_cls<<<(NG * NCLS + 255) / 256, 256, 0, stream>>>(pooled, lin_w, lin_b, out);
}

// Round 5
// 662.778 us; speedup vs baseline: 2.0295x; 1.0602x over previous
//
#include <hip/hip_runtime.h>
#include <hip/hip_bf16.h>
#include <math.h>

#define NN 50000
#define NE 800000
#define FE 16
#define CC 64
#define NG 512
#define NCLS 10
#define NCONV 7
#define SCAN_B 49  // ceil(NN/1024)

struct MlpP { const float* w1; const float* b1; const float* w2; const float* b2; };
struct MlpAll { MlpP p[NCONV]; };

// ---- CSR build ----
__global__ __launch_bounds__(256) void k_hist(const int* __restrict__ ecol, int* __restrict__ cnt) {
  int e = blockIdx.x * 256 + threadIdx.x;
  if (e < NE) atomicAdd(&cnt[ecol[e]], 1);
}

// 3-phase parallel scan of cnt[NN] -> cptr (exclusive), cursor init
__global__ __launch_bounds__(1024) void k_scanA(const int* __restrict__ cnt, int* __restrict__ excl,
                                                int* __restrict__ bsum) {
  __shared__ int sc[1024];
  int t = threadIdx.x;
  int i = blockIdx.x * 1024 + t;
  int v = (i < NN) ? cnt[i] : 0;
  sc[t] = v;
  __syncthreads();
  for (int off = 1; off < 1024; off <<= 1) {
    int u = (t >= off) ? sc[t - off] : 0;
    __syncthreads();
    sc[t] += u;
    __syncthreads();
  }
  if (i < NN) excl[i] = sc[t] - v;
  if (t == 1023) bsum[blockIdx.x] = sc[1023];
}

__global__ void k_scanB(const int* __restrict__ bsum, int* __restrict__ boff) {
  int lane = threadIdx.x;  // 64 threads = 1 wave
  int v = (lane < SCAN_B) ? bsum[lane] : 0;
  int own = v;
  for (int off = 1; off < 64; off <<= 1) {
    int u = __shfl_up(v, off);
    if (lane >= off) v += u;
  }
  if (lane < SCAN_B) boff[lane] = v - own;  // exclusive block offset
}

__global__ __launch_bounds__(1024) void k_scanC(const int* __restrict__ excl, const int* __restrict__ boff,
                                                int* __restrict__ cptr, int* __restrict__ cursor) {
  int i = blockIdx.x * 1024 + threadIdx.x;
  if (i < NN) {
    int p = excl[i] + boff[blockIdx.x];
    cptr[i] = p;
    cursor[i] = p;
  }
  if (i == 0) cptr[NN] = NE;
}

// ---- CSR scatter: csrc[p]=src (4B scatter, 3.2MB), pos[e]=p (coalesced) ----
__global__ __launch_bounds__(256) void k_scatter(
    const int* __restrict__ erow, const int* __restrict__ ecol,
    int* __restrict__ cursor, int* __restrict__ csrc, int* __restrict__ pos) {
  int e = blockIdx.x * 256 + threadIdx.x;
  if (e >= NE) return;
  int c = ecol[e];
  int p = atomicAdd(&cursor[c], 1);
  csrc[p] = erow[e];
  pos[e] = p;
}

// ---- all-7 edge MLPs, TWO edges per thread (amortize scalar weight loads) ----
__global__ __launch_bounds__(256) void k_mlp(
    const int* __restrict__ pos, const float* __restrict__ ea,
    float* __restrict__ wcsr8, MlpAll mw) {
  int ep = blockIdx.x * 256 + threadIdx.x;
  if (ep >= NE / 2) return;
  int e0 = ep * 2;
  float a[2][16];
  #pragma unroll
  for (int t = 0; t < 2; ++t) {
    const float4* ea4 = reinterpret_cast<const float4*>(ea + (size_t)(e0 + t) * 16);
    float4 q0 = ea4[0], q1 = ea4[1], q2 = ea4[2], q3 = ea4[3];
    a[t][0]=q0.x; a[t][1]=q0.y; a[t][2]=q0.z; a[t][3]=q0.w;
    a[t][4]=q1.x; a[t][5]=q1.y; a[t][6]=q1.z; a[t][7]=q1.w;
    a[t][8]=q2.x; a[t][9]=q2.y; a[t][10]=q2.z; a[t][11]=q2.w;
    a[t][12]=q3.x; a[t][13]=q3.y; a[t][14]=q3.z; a[t][15]=q3.w;
  }
  int2 pp = *reinterpret_cast<const int2*>(pos + e0);
  float wv[2][NCONV];
  #pragma unroll
  for (int j = 0; j < NCONV; ++j) {
    const float* w1 = mw.p[j].w1;
    const float* b1 = mw.p[j].b1;
    const float* w2 = mw.p[j].w2;
    float b2v = mw.p[j].b2[0];
    float z0 = b2v, z1 = b2v;
    #pragma unroll
    for (int k = 0; k < 16; ++k) {
      float bk = b1[k];
      float wk = w2[k];
      float h0 = bk, h1 = bk;
      #pragma unroll
      for (int m = 0; m < 16; ++m) {
        float wm = w1[k * 16 + m];
        h0 += a[0][m] * wm;
        h1 += a[1][m] * wm;
      }
      h0 = h0 > 0.f ? h0 : 0.f;
      h1 = h1 > 0.f ? h1 : 0.f;
      z0 += h0 * wk;
      z1 += h1 * wk;
    }
    wv[0][j] = 1.f / (1.f + __expf(-z0));
    wv[1][j] = 1.f / (1.f + __expf(-z1));
  }
  float4* d0 = reinterpret_cast<float4*>(wcsr8 + (size_t)pp.x * 8);
  d0[0] = make_float4(wv[0][0], wv[0][1], wv[0][2], wv[0][3]);
  d0[1] = make_float4(wv[0][4], wv[0][5], wv[0][6], 0.f);
  float4* d1 = reinterpret_cast<float4*>(wcsr8 + (size_t)pp.y * 8);
  d1[0] = make_float4(wv[1][0], wv[1][1], wv[1][2], wv[1][3]);
  d1[1] = make_float4(wv[1][4], wv[1][5], wv[1][6], 0.f);
}

// ---- deg per (node, conv) via CSR gather-sum; fused rsqrt -> dis ----
__global__ __launch_bounds__(256) void k_deg(const float* __restrict__ wcsr8,
                                             const int* __restrict__ cptr,
                                             float* __restrict__ dis) {
  int n = blockIdx.x * 256 + threadIdx.x;
  if (n >= NN) return;
  int lo = cptr[n], hi = cptr[n + 1];
  float s0=0,s1=0,s2=0,s3=0,s4=0,s5=0,s6=0;
  for (int k = lo; k < hi; ++k) {
    const float4* q = reinterpret_cast<const float4*>(wcsr8 + (size_t)k * 8);
    float4 a = q[0], b = q[1];
    s0+=a.x; s1+=a.y; s2+=a.z; s3+=a.w; s4+=b.x; s5+=b.y; s6+=b.z;
  }
  dis[0*NN+n]=rsqrtf(s0+1.f); dis[1*NN+n]=rsqrtf(s1+1.f); dis[2*NN+n]=rsqrtf(s2+1.f);
  dis[3*NN+n]=rsqrtf(s3+1.f); dis[4*NN+n]=rsqrtf(s4+1.f); dis[5*NN+n]=rsqrtf(s5+1.f);
  dis[6*NN+n]=rsqrtf(s6+1.f);
}

// transpose the 7 node-linear weights: lwT[j][ci][co] = lw_j[co][ci]
__global__ __launch_bounds__(256) void k_lwt(const float* __restrict__ c1, const float* __restrict__ h1,
                                             const float* __restrict__ h2, float* __restrict__ lwT) {
  int id = blockIdx.x * 256 + threadIdx.x;
  if (id >= NCONV * CC * CC) return;
  int j = id >> 12;
  int r = id & 4095;
  int co = r >> 6, ci = r & 63;
  const float* src = (j == 0) ? c1 : (j <= 3 ? h1 + (j - 1) * 4096 : h2 + (j - 4) * 4096);
  lwT[j * 4096 + ci * 64 + co] = src[co * 64 + ci];
}

// ---- BatchNorm stats: S and SS per channel ----
__global__ __launch_bounds__(256) void k_bnstat(const float* __restrict__ src, float* __restrict__ accum) {
  __shared__ float sS[256], sQ[256];
  int t = threadIdx.x;
  int c = t & 63, rg = t >> 6;
  int base = blockIdx.x * 196;
  float S = 0.f, Q = 0.f;
  for (int rr = rg; rr < 196; rr += 4) {
    int r = base + rr;
    if (r < NN) { float v = src[r * 64 + c]; S += v; Q += v * v; }
  }
  sS[t] = S; sQ[t] = Q;
  __syncthreads();
  if (t < 128) { sS[t] += sS[t + 128]; sQ[t] += sQ[t + 128]; }
  __syncthreads();
  if (t < 64) {
    atomicAdd(&accum[c], sS[t] + sS[t + 64]);
    atomicAdd(&accum[64 + c], sQ[t] + sQ[t + 64]);
  }
}

// ---- fused (BN+ReLU)? -> GEMM -> *dis : dst = f(src) @ lwT * dis[n] ----
__global__ __launch_bounds__(256) void k_gemm(const float* __restrict__ src, const float* __restrict__ lwT,
                                              const float* __restrict__ accum, const float* __restrict__ dis,
                                              float* __restrict__ dst, int useBN) {
  __shared__ float xs[64 * 65];
  int t = threadIdx.x;
  int rows0 = blockIdx.x * 64;
  // stage 64 rows (float4), fused BN+ReLU
  for (int i = 0; i < 4; ++i) {
    int f = t + i * 256;            // float4 index in [0,1024)
    int r = f >> 4, c4 = (f & 15) * 4;
    int row = rows0 + r;
    float4 v = make_float4(0.f, 0.f, 0.f, 0.f);
    if (row < NN) v = *reinterpret_cast<const float4*>(src + (size_t)row * 64 + c4);
    if (useBN) {
      float4 S = *reinterpret_cast<const float4*>(accum + c4);
      float4 Q = *reinterpret_cast<const float4*>(accum + 64 + c4);
      float mu, var, rs;
      mu = S.x * (1.0f/NN); var = Q.x*(1.0f/NN)-mu*mu; var = var<0.f?0.f:var; rs = rsqrtf(var+1e-5f);
      v.x = (v.x-mu)*rs; v.x = v.x>0.f?v.x:0.f;
      mu = S.y * (1.0f/NN); var = Q.y*(1.0f/NN)-mu*mu; var = var<0.f?0.f:var; rs = rsqrtf(var+1e-5f);
      v.y = (v.y-mu)*rs; v.y = v.y>0.f?v.y:0.f;
      mu = S.z * (1.0f/NN); var = Q.z*(1.0f/NN)-mu*mu; var = var<0.f?0.f:var; rs = rsqrtf(var+1e-5f);
      v.z = (v.z-mu)*rs; v.z = v.z>0.f?v.z:0.f;
      mu = S.w * (1.0f/NN); var = Q.w*(1.0f/NN)-mu*mu; var = var<0.f?0.f:var; rs = rsqrtf(var+1e-5f);
      v.w = (v.w-mu)*rs; v.w = v.w>0.f?v.w:0.f;
    }
    xs[r * 65 + c4 + 0] = v.x;
    xs[r * 65 + c4 + 1] = v.y;
    xs[r * 65 + c4 + 2] = v.z;
    xs[r * 65 + c4 + 3] = v.w;
  }
  __syncthreads();
  int lane = t & 63;
  int cobase = __builtin_amdgcn_readfirstlane((t >> 6) << 4);  // wave-uniform -> scalar weight loads
  float acc[16];
  #pragma unroll
  for (int u = 0; u < 16; ++u) acc[u] = 0.f;
  #pragma unroll 8
  for (int ci = 0; ci < 64; ++ci) {
    float xv = xs[lane * 65 + ci];
    const float* wrow = lwT + ci * 64 + cobase;
    #pragma unroll
    for (int u = 0; u < 16; ++u) acc[u] += xv * wrow[u];
  }
  __syncthreads();
  int row = rows0 + lane;
  float d = (row < NN) ? dis[row] : 0.f;
  #pragma unroll
  for (int u = 0; u < 16; ++u) xs[lane * 65 + cobase + u] = acc[u] * d;
  __syncthreads();
  for (int i = 0; i < 4; ++i) {
    int f = t + i * 256;
    int r = f >> 4, c4 = (f & 15) * 4;
    int orow = rows0 + r;
    if (orow < NN) {
      float4 v = make_float4(xs[r*65+c4], xs[r*65+c4+1], xs[r*65+c4+2], xs[r*65+c4+3]);
      *reinterpret_cast<float4*>(dst + (size_t)orow * 64 + c4) = v;
    }
  }
}

// ---- aggregation: wave per node, lane = channel; 8-deep batched gather ----
// mode 0: out = v
// mode 1: write X1 = v + skipA  (out unused)
// mode 2: sv = relu(v + skipA + skipX1); atomicMax into pooled (int-bits, sv>=0)
__global__ __launch_bounds__(256) void k_agg(const float* __restrict__ T, const float* __restrict__ wj,
                                             const int* __restrict__ csrc, const int* __restrict__ cptr,
                                             const float* __restrict__ dis, float* __restrict__ out,
                                             const float* __restrict__ skipA, const float* __restrict__ skipX1,
                                             float* __restrict__ outX1, const int* __restrict__ batch,
                                             int* __restrict__ poolI, int mode) {
  int t = threadIdx.x;
  int n = blockIdx.x * 4 + (t >> 6);
  if (n >= NN) return;
  int lane = t & 63;
  int lo = cptr[n], hi = cptr[n + 1];
  float acc = T[(size_t)n * 64 + lane];  // self loop (dis[n] folded into T)
  int k = lo;
  for (; k + 8 <= hi; k += 8) {
    int s0=csrc[k+0], s1=csrc[k+1], s2=csrc[k+2], s3=csrc[k+3];
    int s4=csrc[k+4], s5=csrc[k+5], s6=csrc[k+6], s7=csrc[k+7];
    float w0=wj[(size_t)(k+0)*8], w1=wj[(size_t)(k+1)*8], w2=wj[(size_t)(k+2)*8], w3=wj[(size_t)(k+3)*8];
    float w4=wj[(size_t)(k+4)*8], w5=wj[(size_t)(k+5)*8], w6=wj[(size_t)(k+6)*8], w7=wj[(size_t)(k+7)*8];
    float t0=T[(size_t)s0*64+lane], t1=T[(size_t)s1*64+lane], t2=T[(size_t)s2*64+lane], t3=T[(size_t)s3*64+lane];
    float t4=T[(size_t)s4*64+lane], t5=T[(size_t)s5*64+lane], t6=T[(size_t)s6*64+lane], t7=T[(size_t)s7*64+lane];
    acc += w0*t0; acc += w1*t1; acc += w2*t2; acc += w3*t3;
    acc += w4*t4; acc += w5*t5; acc += w6*t6; acc += w7*t7;
  }
  for (; k + 4 <= hi; k += 4) {
    int s0=csrc[k+0], s1=csrc[k+1], s2=csrc[k+2], s3=csrc[k+3];
    float w0=wj[(size_t)(k+0)*8], w1=wj[(size_t)(k+1)*8], w2=wj[(size_t)(k+2)*8], w3=wj[(size_t)(k+3)*8];
    float t0=T[(size_t)s0*64+lane], t1=T[(size_t)s1*64+lane], t2=T[(size_t)s2*64+lane], t3=T[(size_t)s3*64+lane];
    acc += w0*t0; acc += w1*t1; acc += w2*t2; acc += w3*t3;
  }
  for (; k < hi; ++k) {
    int s0 = csrc[k];
    float w0 = wj[(size_t)k * 8];
    acc += w0 * T[(size_t)s0 * 64 + lane];
  }
  float v = dis[n] * acc;
  size_t idx = (size_t)n * 64 + lane;
  if (mode == 1) {
    outX1[idx] = v + skipA[idx];
  } else if (mode == 2) {
    float sv = v + skipA[idx] + skipX1[idx];
    sv = sv > 0.f ? sv : 0.f;
    int g = batch[n];
    atomicMax(&poolI[(size_t)g * 64 + lane], __float_as_int(sv));
  } else {
    out[idx] = v;
  }
}

__global__ __launch_bounds__(256) void k_cls(const float* __restrict__ pooled, const float* __restrict__ lw,
                                             const float* __restrict__ lb, float* __restrict__ out) {
  int id = blockIdx.x * 256 + threadIdx.x;
  if (id >= NG * NCLS) return;
  int g = id / NCLS, k = id % NCLS;
  float acc = lb[k];
  #pragma unroll 8
  for (int c = 0; c < 64; ++c) acc += pooled[g * 64 + c] * lw[k * 64 + c];
  out[id] = acc;
}

extern "C" void kernel_launch(void* const* d_in, const int* in_sizes, int n_in,
                              void* d_out, int out_size, void* d_ws, size_t ws_size,
                              hipStream_t stream) {
  (void)in_sizes; (void)n_in; (void)out_size; (void)ws_size;
  const float* x     = (const float*)d_in[0];
  const int*   ei    = (const int*)d_in[1];
  const int*   batch = (const int*)d_in[2];
  // d_in[3] = dropout (0) -- unused
  const float* ea    = (const float*)d_in[4];
  const float* c1_lw = (const float*)d_in[5];
  const float* c1_w1 = (const float*)d_in[6];
  const float* c1_b1 = (const float*)d_in[7];
  const float* c1_w2 = (const float*)d_in[8];
  const float* c1_b2 = (const float*)d_in[9];
  const float* h1_lw = (const float*)d_in[10];
  const float* h1_w1 = (const float*)d_in[11];
  const float* h1_b1 = (const float*)d_in[12];
  const float* h1_w2 = (const float*)d_in[13];
  const float* h1_b2 = (const float*)d_in[14];
  const float* h2_lw = (const float*)d_in[15];
  const float* h2_w1 = (const float*)d_in[16];
  const float* h2_b1 = (const float*)d_in[17];
  const float* h2_w2 = (const float*)d_in[18];
  const float* h2_b2 = (const float*)d_in[19];
  const float* lin_w = (const float*)d_in[20];
  const float* lin_b = (const float*)d_in[21];
  float* out = (float*)d_out;

  char* base = (char*)d_ws;
  size_t off = 0;
  auto alloc = [&](size_t bytes) -> size_t {
    size_t o = off;
    off = (off + bytes + 255) & ~(size_t)255;
    return o;
  };
  size_t o_wcsr8  = alloc((size_t)NE * 8 * 4);        // 25.6MB, CSR order, 8 floats/edge
  size_t o_csrc   = alloc((size_t)NE * 4);
  size_t o_pos    = alloc((size_t)NE * 4);
  size_t o_cptr   = alloc((size_t)(NN + 1) * 4);
  size_t o_excl   = alloc((size_t)NN * 4);
  size_t o_bsum   = alloc((size_t)64 * 4);
  size_t o_boff   = alloc((size_t)64 * 4);
  size_t o_cnt    = alloc((size_t)NN * 4);            // zeroed region starts here (cnt -> cursor)
  size_t o_accum  = alloc((size_t)6 * 128 * 4);       // zeroed region ends after this
  size_t o_dis    = alloc((size_t)NCONV * NN * 4);
  size_t o_lwt    = alloc((size_t)NCONV * 4096 * 4);
  size_t o_T      = alloc((size_t)NN * 64 * 4);
  size_t o_A      = alloc((size_t)NN * 64 * 4);
  size_t o_B      = alloc((size_t)NN * 64 * 4);
  size_t o_X1     = alloc((size_t)NN * 64 * 4);
  size_t o_pool   = alloc((size_t)NG * 64 * 4);

  float* wcsr8  = (float*)(base + o_wcsr8);
  int*   csrc   = (int*)(base + o_csrc);
  int*   pos    = (int*)(base + o_pos);
  int*   cptr   = (int*)(base + o_cptr);
  int*   excl   = (int*)(base + o_excl);
  int*   bsum   = (int*)(base + o_bsum);
  int*   boff   = (int*)(base + o_boff);
  int*   cnt    = (int*)(base + o_cnt);   // doubles as cursor after scanC
  float* accum  = (float*)(base + o_accum);
  float* dis    = (float*)(base + o_dis);
  float* lwt    = (float*)(base + o_lwt);
  float* T      = (float*)(base + o_T);
  float* A      = (float*)(base + o_A);
  float* B      = (float*)(base + o_B);
  float* X1     = (float*)(base + o_X1);
  float* pooled = (float*)(base + o_pool);

  // zero: cnt + accum (contiguous), and pooled (atomicMax target; relu values >= 0)
  hipMemsetAsync(base + o_cnt, 0, o_dis - o_cnt, stream);
  hipMemsetAsync(base + o_pool, 0, (size_t)NG * 64 * 4, stream);

  const int* erow = ei;
  const int* ecol = ei + NE;

  k_hist<<<(NE + 255) / 256, 256, 0, stream>>>(ecol, cnt);
  k_scanA<<<SCAN_B, 1024, 0, stream>>>(cnt, excl, bsum);
  k_scanB<<<1, 64, 0, stream>>>(bsum, boff);
  k_scanC<<<SCAN_B, 1024, 0, stream>>>(excl, boff, cptr, cnt);
  k_scatter<<<(NE + 255) / 256, 256, 0, stream>>>(erow, ecol, cnt, csrc, pos);

  MlpAll mw;
  mw.p[0] = {c1_w1, c1_b1, c1_w2, c1_b2};
  for (int i = 0; i < 3; ++i) {
    mw.p[1 + i] = {h1_w1 + i * 256, h1_b1 + i * 16, h1_w2 + i * 16, h1_b2 + i};
    mw.p[4 + i] = {h2_w1 + i * 256, h2_b1 + i * 16, h2_w2 + i * 16, h2_b2 + i};
  }
  k_mlp<<<(NE / 2 + 255) / 256, 256, 0, stream>>>(pos, ea, wcsr8, mw);
  k_deg<<<(NN + 255) / 256, 256, 0, stream>>>(wcsr8, cptr, dis);
  k_lwt<<<(NCONV * 4096) / 256, 256, 0, stream>>>(c1_lw, h1_lw, h2_lw, lwt);

  const int GB = (NN + 63) / 64;  // 782
  const int AB = (NN + 3) / 4;    // 12500

  // conv1 -> A (= x0)
  k_gemm<<<GB, 256, 0, stream>>>(x, lwt, nullptr, dis, T, 0);
  k_agg<<<AB, 256, 0, stream>>>(T, wcsr8 + 0, csrc, cptr, dis, A,
                                nullptr, nullptr, nullptr, nullptr, nullptr, 0);

  // hidden loop 1: x = conv(relu(BN(x))); after i==2 fuse x1 = x + x0 -> X1 only
  for (int i = 0; i < 3; ++i) {
    const float* src = (i == 0) ? A : B;
    k_bnstat<<<256, 256, 0, stream>>>(src, accum + i * 128);
    k_gemm<<<GB, 256, 0, stream>>>(src, lwt + (1 + i) * 4096, accum + i * 128,
                                   dis + (size_t)(1 + i) * NN, T, 1);
    int mode = (i == 2) ? 1 : 0;
    k_agg<<<AB, 256, 0, stream>>>(T, wcsr8 + (1 + i), csrc, cptr,
                                  dis + (size_t)(1 + i) * NN, B, A, nullptr, X1,
                                  nullptr, nullptr, mode);
  }
  // hidden loop 2 (input = X1); after i==2 fuse x2=relu(x+x0+x1) + max-pool via atomics
  for (int i = 0; i < 3; ++i) {
    const float* src = (i == 0) ? X1 : B;
    k_bnstat<<<256, 256, 0, stream>>>(src, accum + (3 + i) * 128);
    k_gemm<<<GB, 256, 0, stream>>>(src, lwt + (4 + i) * 4096, accum + (3 + i) * 128,
                                   dis + (size_t)(4 + i) * NN, T, 1);
    int mode = (i == 2) ? 2 : 0;
    k_agg<<<AB, 256, 0, stream>>>(T, wcsr8 + (4 + i), csrc, cptr,
                                  dis + (size_t)(4 + i) * NN, B, A, X1, nullptr,
                                  batch, (int*)pooled, mode);
  }

  k_cls<<<(NG * NCLS + 255) / 256, 256, 0, stream>>>(pooled, lin_w, lin_b, out);
}

// Round 6
// 644.460 us; speedup vs baseline: 2.0871x; 1.0284x over previous
//
#include <hip/hip_runtime.h>
#include <hip/hip_bf16.h>
#include <math.h>

#define NN 50000
#define NE 800000
#define FE 16
#define CC 64
#define NG 512
#define NCLS 10
#define NCONV 7
#define SCAN_B 49  // ceil(NN/1024)

typedef float v2f __attribute__((ext_vector_type(2)));

struct MlpP { const float* w1; const float* b1; const float* w2; const float* b2; };
struct MlpAll { MlpP p[NCONV]; };

// ---- CSR build ----
__global__ __launch_bounds__(256) void k_hist(const int* __restrict__ ecol, int* __restrict__ cnt) {
  int e = blockIdx.x * 256 + threadIdx.x;
  if (e < NE) atomicAdd(&cnt[ecol[e]], 1);
}

// 3-phase parallel scan of cnt[NN] -> cptr (exclusive), cursor init
__global__ __launch_bounds__(1024) void k_scanA(const int* __restrict__ cnt, int* __restrict__ excl,
                                                int* __restrict__ bsum) {
  __shared__ int sc[1024];
  int t = threadIdx.x;
  int i = blockIdx.x * 1024 + t;
  int v = (i < NN) ? cnt[i] : 0;
  sc[t] = v;
  __syncthreads();
  for (int off = 1; off < 1024; off <<= 1) {
    int u = (t >= off) ? sc[t - off] : 0;
    __syncthreads();
    sc[t] += u;
    __syncthreads();
  }
  if (i < NN) excl[i] = sc[t] - v;
  if (t == 1023) bsum[blockIdx.x] = sc[1023];
}

__global__ void k_scanB(const int* __restrict__ bsum, int* __restrict__ boff) {
  int lane = threadIdx.x;  // 64 threads = 1 wave
  int v = (lane < SCAN_B) ? bsum[lane] : 0;
  int own = v;
  for (int off = 1; off < 64; off <<= 1) {
    int u = __shfl_up(v, off);
    if (lane >= off) v += u;
  }
  if (lane < SCAN_B) boff[lane] = v - own;  // exclusive block offset
}

__global__ __launch_bounds__(1024) void k_scanC(const int* __restrict__ excl, const int* __restrict__ boff,
                                                int* __restrict__ cptr, int* __restrict__ cursor) {
  int i = blockIdx.x * 1024 + threadIdx.x;
  if (i < NN) {
    int p = excl[i] + boff[blockIdx.x];
    cptr[i] = p;
    cursor[i] = p;
  }
  if (i == 0) cptr[NN] = NE;
}

// ---- CSR scatter: csrc[p]=src (4B scatter, 3.2MB), pos[e]=p (coalesced) ----
__global__ __launch_bounds__(256) void k_scatter(
    const int* __restrict__ erow, const int* __restrict__ ecol,
    int* __restrict__ cursor, int* __restrict__ csrc, int* __restrict__ pos) {
  int e = blockIdx.x * 256 + threadIdx.x;
  if (e >= NE) return;
  int c = ecol[e];
  int p = atomicAdd(&cursor[c], 1);
  csrc[p] = erow[e];
  pos[e] = p;
}

// ---- all-7 edge MLPs, TWO edges per thread PACKED as float2 (target v_pk_fma_f32) ----
__global__ __launch_bounds__(256) void k_mlp(
    const int* __restrict__ pos, const float* __restrict__ ea,
    float* __restrict__ wcsr8, MlpAll mw) {
  int ep = blockIdx.x * 256 + threadIdx.x;
  if (ep >= NE / 2) return;
  int e0 = ep * 2;
  const float4* eaA = reinterpret_cast<const float4*>(ea + (size_t)e0 * 16);
  const float4* eaB = reinterpret_cast<const float4*>(ea + (size_t)(e0 + 1) * 16);
  float4 A0 = eaA[0], A1 = eaA[1], A2 = eaA[2], A3 = eaA[3];
  float4 B0 = eaB[0], B1 = eaB[1], B2 = eaB[2], B3 = eaB[3];
  v2f a2[16];
  a2[0]  = (v2f){A0.x, B0.x}; a2[1]  = (v2f){A0.y, B0.y}; a2[2]  = (v2f){A0.z, B0.z}; a2[3]  = (v2f){A0.w, B0.w};
  a2[4]  = (v2f){A1.x, B1.x}; a2[5]  = (v2f){A1.y, B1.y}; a2[6]  = (v2f){A1.z, B1.z}; a2[7]  = (v2f){A1.w, B1.w};
  a2[8]  = (v2f){A2.x, B2.x}; a2[9]  = (v2f){A2.y, B2.y}; a2[10] = (v2f){A2.z, B2.z}; a2[11] = (v2f){A2.w, B2.w};
  a2[12] = (v2f){A3.x, B3.x}; a2[13] = (v2f){A3.y, B3.y}; a2[14] = (v2f){A3.z, B3.z}; a2[15] = (v2f){A3.w, B3.w};
  int2 pp = *reinterpret_cast<const int2*>(pos + e0);
  float wv0[NCONV], wv1[NCONV];
  #pragma unroll
  for (int j = 0; j < NCONV; ++j) {
    const float* w1 = mw.p[j].w1;
    const float* b1 = mw.p[j].b1;
    const float* w2 = mw.p[j].w2;
    float b2v = mw.p[j].b2[0];
    v2f z = {b2v, b2v};
    #pragma unroll
    for (int k = 0; k < 16; ++k) {
      float bk = b1[k];
      float wk = w2[k];
      v2f h = {bk, bk};
      #pragma unroll
      for (int m = 0; m < 16; ++m) {
        h += a2[m] * w1[k * 16 + m];   // packed: 1 v_pk_fma_f32 for both edges
      }
      h.x = h.x > 0.f ? h.x : 0.f;
      h.y = h.y > 0.f ? h.y : 0.f;
      z += h * wk;
    }
    wv0[j] = 1.f / (1.f + __expf(-z.x));
    wv1[j] = 1.f / (1.f + __expf(-z.y));
  }
  float4* d0 = reinterpret_cast<float4*>(wcsr8 + (size_t)pp.x * 8);
  d0[0] = make_float4(wv0[0], wv0[1], wv0[2], wv0[3]);
  d0[1] = make_float4(wv0[4], wv0[5], wv0[6], 0.f);
  float4* d1 = reinterpret_cast<float4*>(wcsr8 + (size_t)pp.y * 8);
  d1[0] = make_float4(wv1[0], wv1[1], wv1[2], wv1[3]);
  d1[1] = make_float4(wv1[4], wv1[5], wv1[6], 0.f);
}

// ---- repack wcsr8 chunks -> 7 dense CSR-order planes (all coalesced) ----
__global__ __launch_bounds__(256) void k_repack(const float* __restrict__ wcsr8, float* __restrict__ wpl) {
  int p = blockIdx.x * 256 + threadIdx.x;
  if (p >= NE) return;
  const float4* q = reinterpret_cast<const float4*>(wcsr8 + (size_t)p * 8);
  float4 a = q[0], b = q[1];
  wpl[0 * (size_t)NE + p] = a.x;
  wpl[1 * (size_t)NE + p] = a.y;
  wpl[2 * (size_t)NE + p] = a.z;
  wpl[3 * (size_t)NE + p] = a.w;
  wpl[4 * (size_t)NE + p] = b.x;
  wpl[5 * (size_t)NE + p] = b.y;
  wpl[6 * (size_t)NE + p] = b.z;
}

// ---- deg per (node, conv) via CSR gather-sum; fused rsqrt -> dis ----
__global__ __launch_bounds__(256) void k_deg(const float* __restrict__ wcsr8,
                                             const int* __restrict__ cptr,
                                             float* __restrict__ dis) {
  int n = blockIdx.x * 256 + threadIdx.x;
  if (n >= NN) return;
  int lo = cptr[n], hi = cptr[n + 1];
  float s0=0,s1=0,s2=0,s3=0,s4=0,s5=0,s6=0;
  for (int k = lo; k < hi; ++k) {
    const float4* q = reinterpret_cast<const float4*>(wcsr8 + (size_t)k * 8);
    float4 a = q[0], b = q[1];
    s0+=a.x; s1+=a.y; s2+=a.z; s3+=a.w; s4+=b.x; s5+=b.y; s6+=b.z;
  }
  dis[0*NN+n]=rsqrtf(s0+1.f); dis[1*NN+n]=rsqrtf(s1+1.f); dis[2*NN+n]=rsqrtf(s2+1.f);
  dis[3*NN+n]=rsqrtf(s3+1.f); dis[4*NN+n]=rsqrtf(s4+1.f); dis[5*NN+n]=rsqrtf(s5+1.f);
  dis[6*NN+n]=rsqrtf(s6+1.f);
}

// transpose the 7 node-linear weights: lwT[j][ci][co] = lw_j[co][ci]
__global__ __launch_bounds__(256) void k_lwt(const float* __restrict__ c1, const float* __restrict__ h1,
                                             const float* __restrict__ h2, float* __restrict__ lwT) {
  int id = blockIdx.x * 256 + threadIdx.x;
  if (id >= NCONV * CC * CC) return;
  int j = id >> 12;
  int r = id & 4095;
  int co = r >> 6, ci = r & 63;
  const float* src = (j == 0) ? c1 : (j <= 3 ? h1 + (j - 1) * 4096 : h2 + (j - 4) * 4096);
  lwT[j * 4096 + ci * 64 + co] = src[co * 64 + ci];
}

// ---- BatchNorm stats: S and SS per channel ----
__global__ __launch_bounds__(256) void k_bnstat(const float* __restrict__ src, float* __restrict__ accum) {
  __shared__ float sS[256], sQ[256];
  int t = threadIdx.x;
  int c = t & 63, rg = t >> 6;
  int base = blockIdx.x * 196;
  float S = 0.f, Q = 0.f;
  for (int rr = rg; rr < 196; rr += 4) {
    int r = base + rr;
    if (r < NN) { float v = src[r * 64 + c]; S += v; Q += v * v; }
  }
  sS[t] = S; sQ[t] = Q;
  __syncthreads();
  if (t < 128) { sS[t] += sS[t + 128]; sQ[t] += sQ[t + 128]; }
  __syncthreads();
  if (t < 64) {
    atomicAdd(&accum[c], sS[t] + sS[t + 64]);
    atomicAdd(&accum[64 + c], sQ[t] + sQ[t + 64]);
  }
}

// ---- fused (BN+ReLU)? -> GEMM -> *dis : dst = f(src) @ lwT * dis[n] ----
__global__ __launch_bounds__(256) void k_gemm(const float* __restrict__ src, const float* __restrict__ lwT,
                                              const float* __restrict__ accum, const float* __restrict__ dis,
                                              float* __restrict__ dst, int useBN) {
  __shared__ float xs[64 * 65];
  int t = threadIdx.x;
  int rows0 = blockIdx.x * 64;
  // stage 64 rows (float4), fused BN+ReLU
  for (int i = 0; i < 4; ++i) {
    int f = t + i * 256;            // float4 index in [0,1024)
    int r = f >> 4, c4 = (f & 15) * 4;
    int row = rows0 + r;
    float4 v = make_float4(0.f, 0.f, 0.f, 0.f);
    if (row < NN) v = *reinterpret_cast<const float4*>(src + (size_t)row * 64 + c4);
    if (useBN) {
      float4 S = *reinterpret_cast<const float4*>(accum + c4);
      float4 Q = *reinterpret_cast<const float4*>(accum + 64 + c4);
      float mu, var, rs;
      mu = S.x * (1.0f/NN); var = Q.x*(1.0f/NN)-mu*mu; var = var<0.f?0.f:var; rs = rsqrtf(var+1e-5f);
      v.x = (v.x-mu)*rs; v.x = v.x>0.f?v.x:0.f;
      mu = S.y * (1.0f/NN); var = Q.y*(1.0f/NN)-mu*mu; var = var<0.f?0.f:var; rs = rsqrtf(var+1e-5f);
      v.y = (v.y-mu)*rs; v.y = v.y>0.f?v.y:0.f;
      mu = S.z * (1.0f/NN); var = Q.z*(1.0f/NN)-mu*mu; var = var<0.f?0.f:var; rs = rsqrtf(var+1e-5f);
      v.z = (v.z-mu)*rs; v.z = v.z>0.f?v.z:0.f;
      mu = S.w * (1.0f/NN); var = Q.w*(1.0f/NN)-mu*mu; var = var<0.f?0.f:var; rs = rsqrtf(var+1e-5f);
      v.w = (v.w-mu)*rs; v.w = v.w>0.f?v.w:0.f;
    }
    xs[r * 65 + c4 + 0] = v.x;
    xs[r * 65 + c4 + 1] = v.y;
    xs[r * 65 + c4 + 2] = v.z;
    xs[r * 65 + c4 + 3] = v.w;
  }
  __syncthreads();
  int lane = t & 63;
  int cobase = __builtin_amdgcn_readfirstlane((t >> 6) << 4);  // wave-uniform -> scalar weight loads
  float acc[16];
  #pragma unroll
  for (int u = 0; u < 16; ++u) acc[u] = 0.f;
  #pragma unroll 8
  for (int ci = 0; ci < 64; ++ci) {
    float xv = xs[lane * 65 + ci];
    const float* wrow = lwT + ci * 64 + cobase;
    #pragma unroll
    for (int u = 0; u < 16; ++u) acc[u] += xv * wrow[u];
  }
  __syncthreads();
  int row = rows0 + lane;
  float d = (row < NN) ? dis[row] : 0.f;
  #pragma unroll
  for (int u = 0; u < 16; ++u) xs[lane * 65 + cobase + u] = acc[u] * d;
  __syncthreads();
  for (int i = 0; i < 4; ++i) {
    int f = t + i * 256;
    int r = f >> 4, c4 = (f & 15) * 4;
    int orow = rows0 + r;
    if (orow < NN) {
      float4 v = make_float4(xs[r*65+c4], xs[r*65+c4+1], xs[r*65+c4+2], xs[r*65+c4+3]);
      *reinterpret_cast<float4*>(dst + (size_t)orow * 64 + c4) = v;
    }
  }
}

// ---- aggregation: wave per node, lane = channel; 8-deep batched gather ----
// wstride: 1 (dense plane) or 8 (wcsr8 fallback)
// mode 0: out = v
// mode 1: write X1 = v + skipA  (out unused)
// mode 2: sv = relu(v + skipA + skipX1); atomicMax into pooled (int-bits, sv>=0)
__global__ __launch_bounds__(256) void k_agg(const float* __restrict__ T, const float* __restrict__ wj,
                                             const int* __restrict__ csrc, const int* __restrict__ cptr,
                                             const float* __restrict__ dis, float* __restrict__ out,
                                             const float* __restrict__ skipA, const float* __restrict__ skipX1,
                                             float* __restrict__ outX1, const int* __restrict__ batch,
                                             int* __restrict__ poolI, int wstride, int mode) {
  int t = threadIdx.x;
  int n = blockIdx.x * 4 + (t >> 6);
  if (n >= NN) return;
  int lane = t & 63;
  int lo = cptr[n], hi = cptr[n + 1];
  float acc = T[(size_t)n * 64 + lane];  // self loop (dis[n] folded into T)
  int k = lo;
  for (; k + 8 <= hi; k += 8) {
    int s0=csrc[k+0], s1=csrc[k+1], s2=csrc[k+2], s3=csrc[k+3];
    int s4=csrc[k+4], s5=csrc[k+5], s6=csrc[k+6], s7=csrc[k+7];
    float w0=wj[(size_t)(k+0)*wstride], w1=wj[(size_t)(k+1)*wstride], w2=wj[(size_t)(k+2)*wstride], w3=wj[(size_t)(k+3)*wstride];
    float w4=wj[(size_t)(k+4)*wstride], w5=wj[(size_t)(k+5)*wstride], w6=wj[(size_t)(k+6)*wstride], w7=wj[(size_t)(k+7)*wstride];
    float t0=T[(size_t)s0*64+lane], t1=T[(size_t)s1*64+lane], t2=T[(size_t)s2*64+lane], t3=T[(size_t)s3*64+lane];
    float t4=T[(size_t)s4*64+lane], t5=T[(size_t)s5*64+lane], t6=T[(size_t)s6*64+lane], t7=T[(size_t)s7*64+lane];
    acc += w0*t0; acc += w1*t1; acc += w2*t2; acc += w3*t3;
    acc += w4*t4; acc += w5*t5; acc += w6*t6; acc += w7*t7;
  }
  for (; k + 4 <= hi; k += 4) {
    int s0=csrc[k+0], s1=csrc[k+1], s2=csrc[k+2], s3=csrc[k+3];
    float w0=wj[(size_t)(k+0)*wstride], w1=wj[(size_t)(k+1)*wstride], w2=wj[(size_t)(k+2)*wstride], w3=wj[(size_t)(k+3)*wstride];
    float t0=T[(size_t)s0*64+lane], t1=T[(size_t)s1*64+lane], t2=T[(size_t)s2*64+lane], t3=T[(size_t)s3*64+lane];
    acc += w0*t0; acc += w1*t1; acc += w2*t2; acc += w3*t3;
  }
  for (; k < hi; ++k) {
    int s0 = csrc[k];
    float w0 = wj[(size_t)k * wstride];
    acc += w0 * T[(size_t)s0 * 64 + lane];
  }
  float v = dis[n] * acc;
  size_t idx = (size_t)n * 64 + lane;
  if (mode == 1) {
    outX1[idx] = v + skipA[idx];
  } else if (mode == 2) {
    float sv = v + skipA[idx] + skipX1[idx];
    sv = sv > 0.f ? sv : 0.f;
    int g = batch[n];
    atomicMax(&poolI[(size_t)g * 64 + lane], __float_as_int(sv));
  } else {
    out[idx] = v;
  }
}

__global__ __launch_bounds__(256) void k_cls(const float* __restrict__ pooled, const float* __restrict__ lw,
                                             const float* __restrict__ lb, float* __restrict__ out) {
  int id = blockIdx.x * 256 + threadIdx.x;
  if (id >= NG * NCLS) return;
  int g = id / NCLS, k = id % NCLS;
  float acc = lb[k];
  #pragma unroll 8
  for (int c = 0; c < 64; ++c) acc += pooled[g * 64 + c] * lw[k * 64 + c];
  out[id] = acc;
}

extern "C" void kernel_launch(void* const* d_in, const int* in_sizes, int n_in,
                              void* d_out, int out_size, void* d_ws, size_t ws_size,
                              hipStream_t stream) {
  (void)in_sizes; (void)n_in; (void)out_size;
  const float* x     = (const float*)d_in[0];
  const int*   ei    = (const int*)d_in[1];
  const int*   batch = (const int*)d_in[2];
  // d_in[3] = dropout (0) -- unused
  const float* ea    = (const float*)d_in[4];
  const float* c1_lw = (const float*)d_in[5];
  const float* c1_w1 = (const float*)d_in[6];
  const float* c1_b1 = (const float*)d_in[7];
  const float* c1_w2 = (const float*)d_in[8];
  const float* c1_b2 = (const float*)d_in[9];
  const float* h1_lw = (const float*)d_in[10];
  const float* h1_w1 = (const float*)d_in[11];
  const float* h1_b1 = (const float*)d_in[12];
  const float* h1_w2 = (const float*)d_in[13];
  const float* h1_b2 = (const float*)d_in[14];
  const float* h2_lw = (const float*)d_in[15];
  const float* h2_w1 = (const float*)d_in[16];
  const float* h2_b1 = (const float*)d_in[17];
  const float* h2_w2 = (const float*)d_in[18];
  const float* h2_b2 = (const float*)d_in[19];
  const float* lin_w = (const float*)d_in[20];
  const float* lin_b = (const float*)d_in[21];
  float* out = (float*)d_out;

  char* base = (char*)d_ws;
  size_t off = 0;
  auto alloc = [&](size_t bytes) -> size_t {
    size_t o = off;
    off = (off + bytes + 255) & ~(size_t)255;
    return o;
  };
  size_t o_wcsr8  = alloc((size_t)NE * 8 * 4);        // 25.6MB, CSR order, 8 floats/edge
  size_t o_csrc   = alloc((size_t)NE * 4);
  size_t o_pos    = alloc((size_t)NE * 4);
  size_t o_cptr   = alloc((size_t)(NN + 1) * 4);
  size_t o_excl   = alloc((size_t)NN * 4);
  size_t o_bsum   = alloc((size_t)64 * 4);
  size_t o_boff   = alloc((size_t)64 * 4);
  size_t o_cnt    = alloc((size_t)NN * 4);            // zeroed region starts here (cnt -> cursor)
  size_t o_accum  = alloc((size_t)6 * 128 * 4);       // zeroed region ends after this
  size_t o_dis    = alloc((size_t)NCONV * NN * 4);
  size_t o_lwt    = alloc((size_t)NCONV * 4096 * 4);
  size_t o_T      = alloc((size_t)NN * 64 * 4);
  size_t o_A      = alloc((size_t)NN * 64 * 4);
  size_t o_B      = alloc((size_t)NN * 64 * 4);
  size_t o_X1     = alloc((size_t)NN * 64 * 4);
  size_t o_pool   = alloc((size_t)NG * 64 * 4);
  size_t o_wpl    = alloc((size_t)NCONV * NE * 4);    // 22.4MB dense planes -- LAST, gated on ws_size
  bool use_planes = (off <= ws_size);

  float* wcsr8  = (float*)(base + o_wcsr8);
  int*   csrc   = (int*)(base + o_csrc);
  int*   pos    = (int*)(base + o_pos);
  int*   cptr   = (int*)(base + o_cptr);
  int*   excl   = (int*)(base + o_excl);
  int*   bsum   = (int*)(base + o_bsum);
  int*   boff   = (int*)(base + o_boff);
  int*   cnt    = (int*)(base + o_cnt);   // doubles as cursor after scanC
  float* accum  = (float*)(base + o_accum);
  float* dis    = (float*)(base + o_dis);
  float* lwt    = (float*)(base + o_lwt);
  float* T      = (float*)(base + o_T);
  float* A      = (float*)(base + o_A);
  float* B      = (float*)(base + o_B);
  float* X1     = (float*)(base + o_X1);
  float* pooled = (float*)(base + o_pool);
  float* wpl    = (float*)(base + o_wpl);

  // zero: cnt + accum (contiguous), and pooled (atomicMax target; relu values >= 0)
  hipMemsetAsync(base + o_cnt, 0, o_dis - o_cnt, stream);
  hipMemsetAsync(base + o_pool, 0, (size_t)NG * 64 * 4, stream);

  const int* erow = ei;
  const int* ecol = ei + NE;

  k_hist<<<(NE + 255) / 256, 256, 0, stream>>>(ecol, cnt);
  k_scanA<<<SCAN_B, 1024, 0, stream>>>(cnt, excl, bsum);
  k_scanB<<<1, 64, 0, stream>>>(bsum, boff);
  k_scanC<<<SCAN_B, 1024, 0, stream>>>(excl, boff, cptr, cnt);
  k_scatter<<<(NE + 255) / 256, 256, 0, stream>>>(erow, ecol, cnt, csrc, pos);

  MlpAll mw;
  mw.p[0] = {c1_w1, c1_b1, c1_w2, c1_b2};
  for (int i = 0; i < 3; ++i) {
    mw.p[1 + i] = {h1_w1 + i * 256, h1_b1 + i * 16, h1_w2 + i * 16, h1_b2 + i};
    mw.p[4 + i] = {h2_w1 + i * 256, h2_b1 + i * 16, h2_w2 + i * 16, h2_b2 + i};
  }
  k_mlp<<<(NE / 2 + 255) / 256, 256, 0, stream>>>(pos, ea, wcsr8, mw);
  if (use_planes) k_repack<<<(NE + 255) / 256, 256, 0, stream>>>(wcsr8, wpl);
  k_deg<<<(NN + 255) / 256, 256, 0, stream>>>(wcsr8, cptr, dis);
  k_lwt<<<(NCONV * 4096) / 256, 256, 0, stream>>>(c1_lw, h1_lw, h2_lw, lwt);

  const int GB = (NN + 63) / 64;  // 782
  const int AB = (NN + 3) / 4;    // 12500
  auto wbase = [&](int j) -> const float* {
    return use_planes ? (wpl + (size_t)j * NE) : (wcsr8 + j);
  };
  const int WS = use_planes ? 1 : 8;

  // conv1 -> A (= x0)
  k_gemm<<<GB, 256, 0, stream>>>(x, lwt, nullptr, dis, T, 0);
  k_agg<<<AB, 256, 0, stream>>>(T, wbase(0), csrc, cptr, dis, A,
                                nullptr, nullptr, nullptr, nullptr, nullptr, WS, 0);

  // hidden loop 1: x = conv(relu(BN(x))); after i==2 fuse x1 = x + x0 -> X1 only
  for (int i = 0; i < 3; ++i) {
    const float* src = (i == 0) ? A : B;
    k_bnstat<<<256, 256, 0, stream>>>(src, accum + i * 128);
    k_gemm<<<GB, 256, 0, stream>>>(src, lwt + (1 + i) * 4096, accum + i * 128,
                                   dis + (size_t)(1 + i) * NN, T, 1);
    int mode = (i == 2) ? 1 : 0;
    k_agg<<<AB, 256, 0, stream>>>(T, wbase(1 + i), csrc, cptr,
                                  dis + (size_t)(1 + i) * NN, B, A, nullptr, X1,
                                  nullptr, nullptr, WS, mode);
  }
  // hidden loop 2 (input = X1); after i==2 fuse x2=relu(x+x0+x1) + max-pool via atomics
  for (int i = 0; i < 3; ++i) {
    const float* src = (i == 0) ? X1 : B;
    k_bnstat<<<256, 256, 0, stream>>>(src, accum + (3 + i) * 128);
    k_gemm<<<GB, 256, 0, stream>>>(src, lwt + (4 + i) * 4096, accum + (3 + i) * 128,
                                   dis + (size_t)(4 + i) * NN, T, 1);
    int mode = (i == 2) ? 2 : 0;
    k_agg<<<AB, 256, 0, stream>>>(T, wbase(4 + i), csrc, cptr,
                                  dis + (size_t)(4 + i) * NN, B, A, X1, nullptr,
                                  batch, (int*)pooled, WS, mode);
  }

  k_cls<<<(NG * NCLS + 255) / 256, 256, 0, stream>>>(pooled, lin_w, lin_b, out);
}